// Round 1
// baseline (16528.535 us; speedup 1.0000x reference)
//
#include <hip/hip_runtime.h>
#include <math.h>

#define HDIM 128
#define TM 64
#define TN 64
#define TK 64

// ---------------- copies ----------------
__global__ __launch_bounds__(256) void copy2_kernel(
    const float* __restrict__ x, const float* __restrict__ hi,
    float* __restrict__ A, float* __restrict__ Bh, int n4) {
  int i = blockIdx.x * 256 + threadIdx.x;
  if (i < n4) {
    reinterpret_cast<float4*>(A)[i]  = reinterpret_cast<const float4*>(x)[i];
    reinterpret_cast<float4*>(Bh)[i] = reinterpret_cast<const float4*>(hi)[i];
  }
}

__global__ __launch_bounds__(256) void copy1_kernel(
    const float* __restrict__ s, float* __restrict__ d, int n4) {
  int i = blockIdx.x * 256 + threadIdx.x;
  if (i < n4) reinterpret_cast<float4*>(d)[i] = reinterpret_cast<const float4*>(s)[i];
}

// ---------------- scatter-add over edges ----------------
// 32 threads per edge, each handles 4 consecutive floats (float4 gather + 4 atomics).
__global__ __launch_bounds__(256) void scatter2_kernel(
    const int* __restrict__ edg, const float* __restrict__ x,
    const float* __restrict__ hi, float* __restrict__ A,
    float* __restrict__ Bh, int E) {
  int idx = blockIdx.x * 256 + threadIdx.x;
  int e = idx >> 5;
  if (e >= E) return;
  int c = (idx & 31) << 2;
  int src = edg[e];
  int dst = edg[E + e];
  const float4 xv = *reinterpret_cast<const float4*>(x  + (size_t)src * HDIM + c);
  const float4 hv = *reinterpret_cast<const float4*>(hi + (size_t)src * HDIM + c);
  float* ap = A + (size_t)dst * HDIM + c;
  atomicAdd(ap + 0, xv.x); atomicAdd(ap + 1, xv.y);
  atomicAdd(ap + 2, xv.z); atomicAdd(ap + 3, xv.w);
  float* bp = Bh + (size_t)dst * HDIM + c;
  atomicAdd(bp + 0, hv.x); atomicAdd(bp + 1, hv.y);
  atomicAdd(bp + 2, hv.z); atomicAdd(bp + 3, hv.w);
}

__global__ __launch_bounds__(256) void scatter1_kernel(
    const int* __restrict__ edg, const float* __restrict__ Corig,
    float* __restrict__ Ctot, int E) {
  int idx = blockIdx.x * 256 + threadIdx.x;
  int e = idx >> 5;
  if (e >= E) return;
  int c = (idx & 31) << 2;
  int src = edg[e];
  int dst = edg[E + e];
  const float4 v = *reinterpret_cast<const float4*>(Corig + (size_t)src * HDIM + c);
  float* p = Ctot + (size_t)dst * HDIM + c;
  atomicAdd(p + 0, v.x); atomicAdd(p + 1, v.y);
  atomicAdd(p + 2, v.z); atomicAdd(p + 3, v.w);
}

// ---------------- fused gate GEMM ----------------
// blockIdx.y = gi in 0..5: group = gi>>1 (0:z, 1:r, 2:h~ partial), half = gi&1
// acc = A@Wx[group][:, half*64:half*64+64]  (+ Bh@Wh[group] for groups 0,1) + biases
// group 0 -> zpre ; group 1 -> Corig = sigmoid(.)*h_i ; group 2 -> hpre (stored in outi)
__global__ __launch_bounds__(256) void gemm3_kernel(
    const float* __restrict__ A, const float* __restrict__ Bh,
    const float* __restrict__ W, const float* __restrict__ b,
    const float* __restrict__ hi, float* __restrict__ zpre,
    float* __restrict__ Corig, float* __restrict__ hpre, int N) {
  __shared__ float At[TK * 65];
  __shared__ float Wt[TK * TN];
  const int t = threadIdx.x;
  const int tr = t >> 4;
  const int tc = t & 15;
  const int rowbase = blockIdx.x * TM;
  const int gi = blockIdx.y;
  const int group = gi >> 1;
  const int half = gi & 1;
  const int gate_x = group * 2;
  const int gate_h = group * 2 + 1;
  float acc[4][4] = {{0.f, 0.f, 0.f, 0.f}, {0.f, 0.f, 0.f, 0.f},
                     {0.f, 0.f, 0.f, 0.f}, {0.f, 0.f, 0.f, 0.f}};

  const int nphase = (group < 2) ? 2 : 1;
  for (int phase = 0; phase < nphase; ++phase) {
    const float* __restrict__ src = (phase == 0) ? A : Bh;
    const int gate = (phase == 0) ? gate_x : gate_h;
    const float* __restrict__ wp = W + (size_t)gate * HDIM * HDIM + half * TN;
    for (int kc = 0; kc < HDIM; kc += TK) {
      // A tile: TM rows x TK k, stored transposed At[k][row] (stride 65)
      #pragma unroll
      for (int i = 0; i < 4; ++i) {
        int flat = i * 256 + t;
        int r = flat >> 4;
        int k4 = (flat & 15) << 2;
        int row = rowbase + r;
        float4 v = make_float4(0.f, 0.f, 0.f, 0.f);
        if (row < N)
          v = *reinterpret_cast<const float4*>(src + (size_t)row * HDIM + kc + k4);
        At[(k4 + 0) * 65 + r] = v.x;
        At[(k4 + 1) * 65 + r] = v.y;
        At[(k4 + 2) * 65 + r] = v.z;
        At[(k4 + 3) * 65 + r] = v.w;
      }
      // W tile: TK x TN (row-major, stride TN)
      #pragma unroll
      for (int i = 0; i < 4; ++i) {
        int flat = i * 256 + t;
        int k = flat >> 4;
        int c4 = (flat & 15) << 2;
        *reinterpret_cast<float4*>(&Wt[k * TN + c4]) =
            *reinterpret_cast<const float4*>(wp + (size_t)(kc + k) * HDIM + c4);
      }
      __syncthreads();
      #pragma unroll 8
      for (int k = 0; k < TK; ++k) {
        float a0 = At[k * 65 + tr * 4 + 0];
        float a1 = At[k * 65 + tr * 4 + 1];
        float a2 = At[k * 65 + tr * 4 + 2];
        float a3 = At[k * 65 + tr * 4 + 3];
        float4 bv = *reinterpret_cast<const float4*>(&Wt[k * TN + tc * 4]);
        acc[0][0] += a0 * bv.x; acc[0][1] += a0 * bv.y; acc[0][2] += a0 * bv.z; acc[0][3] += a0 * bv.w;
        acc[1][0] += a1 * bv.x; acc[1][1] += a1 * bv.y; acc[1][2] += a1 * bv.z; acc[1][3] += a1 * bv.w;
        acc[2][0] += a2 * bv.x; acc[2][1] += a2 * bv.y; acc[2][2] += a2 * bv.z; acc[2][3] += a2 * bv.w;
        acc[3][0] += a3 * bv.x; acc[3][1] += a3 * bv.y; acc[3][2] += a3 * bv.z; acc[3][3] += a3 * bv.w;
      }
      __syncthreads();
    }
  }

  const int colg = half * TN + tc * 4;  // column within gate space [0,128)
  float bias[4];
  #pragma unroll
  for (int cc = 0; cc < 4; ++cc) {
    float bb = b[gate_x * HDIM + colg + cc];
    if (group < 2) bb += b[gate_h * HDIM + colg + cc];
    bias[cc] = bb;
  }
  #pragma unroll
  for (int rr = 0; rr < 4; ++rr) {
    int row = rowbase + tr * 4 + rr;
    if (row >= N) continue;
    size_t base = (size_t)row * HDIM + colg;
    if (group == 0) {
      #pragma unroll
      for (int cc = 0; cc < 4; ++cc) zpre[base + cc] = acc[rr][cc] + bias[cc];
    } else if (group == 1) {
      #pragma unroll
      for (int cc = 0; cc < 4; ++cc) {
        float v = acc[rr][cc] + bias[cc];
        float r = 1.f / (1.f + expf(-v));
        Corig[base + cc] = r * hi[base + cc];
      }
    } else {
      #pragma unroll
      for (int cc = 0; cc < 4; ++cc) hpre[base + cc] = acc[rr][cc] + bias[cc];
    }
  }
}

// ---------------- final GEMM + GRU combine ----------------
// acc = Ctot @ W5[:, half*64:...]; v = acc + b5 + hpre(outi); h~ = tanh(v);
// z = sigmoid(zpre); outi = z*h_i + (1-z)*h~
__global__ __launch_bounds__(256) void gemm_final_kernel(
    const float* __restrict__ Ctot, const float* __restrict__ W5,
    const float* __restrict__ b5, const float* __restrict__ zpre,
    const float* __restrict__ hi, float* __restrict__ outi, int N) {
  __shared__ float At[TK * 65];
  __shared__ float Wt[TK * TN];
  const int t = threadIdx.x;
  const int tr = t >> 4;
  const int tc = t & 15;
  const int rowbase = blockIdx.x * TM;
  const int half = blockIdx.y;
  const float* __restrict__ wp = W5 + half * TN;
  float acc[4][4] = {{0.f, 0.f, 0.f, 0.f}, {0.f, 0.f, 0.f, 0.f},
                     {0.f, 0.f, 0.f, 0.f}, {0.f, 0.f, 0.f, 0.f}};

  for (int kc = 0; kc < HDIM; kc += TK) {
    #pragma unroll
    for (int i = 0; i < 4; ++i) {
      int flat = i * 256 + t;
      int r = flat >> 4;
      int k4 = (flat & 15) << 2;
      int row = rowbase + r;
      float4 v = make_float4(0.f, 0.f, 0.f, 0.f);
      if (row < N)
        v = *reinterpret_cast<const float4*>(Ctot + (size_t)row * HDIM + kc + k4);
      At[(k4 + 0) * 65 + r] = v.x;
      At[(k4 + 1) * 65 + r] = v.y;
      At[(k4 + 2) * 65 + r] = v.z;
      At[(k4 + 3) * 65 + r] = v.w;
    }
    #pragma unroll
    for (int i = 0; i < 4; ++i) {
      int flat = i * 256 + t;
      int k = flat >> 4;
      int c4 = (flat & 15) << 2;
      *reinterpret_cast<float4*>(&Wt[k * TN + c4]) =
          *reinterpret_cast<const float4*>(wp + (size_t)(kc + k) * HDIM + c4);
    }
    __syncthreads();
    #pragma unroll 8
    for (int k = 0; k < TK; ++k) {
      float a0 = At[k * 65 + tr * 4 + 0];
      float a1 = At[k * 65 + tr * 4 + 1];
      float a2 = At[k * 65 + tr * 4 + 2];
      float a3 = At[k * 65 + tr * 4 + 3];
      float4 bv = *reinterpret_cast<const float4*>(&Wt[k * TN + tc * 4]);
      acc[0][0] += a0 * bv.x; acc[0][1] += a0 * bv.y; acc[0][2] += a0 * bv.z; acc[0][3] += a0 * bv.w;
      acc[1][0] += a1 * bv.x; acc[1][1] += a1 * bv.y; acc[1][2] += a1 * bv.z; acc[1][3] += a1 * bv.w;
      acc[2][0] += a2 * bv.x; acc[2][1] += a2 * bv.y; acc[2][2] += a2 * bv.z; acc[2][3] += a2 * bv.w;
      acc[3][0] += a3 * bv.x; acc[3][1] += a3 * bv.y; acc[3][2] += a3 * bv.z; acc[3][3] += a3 * bv.w;
    }
    __syncthreads();
  }

  const int colg = half * TN + tc * 4;
  #pragma unroll
  for (int rr = 0; rr < 4; ++rr) {
    int row = rowbase + tr * 4 + rr;
    if (row >= N) continue;
    size_t base = (size_t)row * HDIM + colg;
    #pragma unroll
    for (int cc = 0; cc < 4; ++cc) {
      float v = acc[rr][cc] + b5[colg + cc] + outi[base + cc];
      float ht = tanhf(v);
      float z = 1.f / (1.f + expf(-zpre[base + cc]));
      outi[base + cc] = z * hi[base + cc] + (1.f - z) * ht;
    }
  }
}

extern "C" void kernel_launch(void* const* d_in, const int* in_sizes, int n_in,
                              void* d_out, int out_size, void* d_ws, size_t ws_size,
                              hipStream_t stream) {
  const float* inp = (const float*)d_in[0];
  const int*   edg = (const int*)d_in[1];
  const float* h   = (const float*)d_in[2];
  const float* W   = (const float*)d_in[3];
  const float* b   = (const float*)d_in[4];
  float* out = (float*)d_out;

  const int NH = in_sizes[0];      // N*H
  const int N  = NH / HDIM;
  const int E  = in_sizes[1] / 2;
  const int L  = in_sizes[2] / NH;

  float* buf0 = (float*)d_ws;            // A, then Ctot
  float* buf1 = buf0 + (size_t)NH;       // Bh
  float* buf2 = buf1 + (size_t)NH;       // zpre
  float* buf3 = buf2 + (size_t)NH;       // Corig

  const int n4 = NH / 4;
  const int cpblocks = (n4 + 255) / 256;
  const int scblocks = (int)(((long long)E * 32 + 255) / 256);
  const int rowblocks = (N + TM - 1) / TM;

  const float* x = inp;
  for (int i = 0; i < L; ++i) {
    const float* hi = h + (size_t)i * NH;
    const float* Wi = W + (size_t)i * 6 * HDIM * HDIM;
    const float* bi = b + (size_t)i * 6 * HDIM;
    float* outi = out + (size_t)i * NH;

    hipLaunchKernelGGL(copy2_kernel, dim3(cpblocks), dim3(256), 0, stream,
                       x, hi, buf0, buf1, n4);
    hipLaunchKernelGGL(scatter2_kernel, dim3(scblocks), dim3(256), 0, stream,
                       edg, x, hi, buf0, buf1, E);
    hipLaunchKernelGGL(gemm3_kernel, dim3(rowblocks, 6), dim3(256), 0, stream,
                       buf0, buf1, Wi, bi, hi, buf2, buf3, outi, N);
    hipLaunchKernelGGL(copy1_kernel, dim3(cpblocks), dim3(256), 0, stream,
                       buf3, buf0, n4);
    hipLaunchKernelGGL(scatter1_kernel, dim3(scblocks), dim3(256), 0, stream,
                       edg, buf3, buf0, E);
    hipLaunchKernelGGL(gemm_final_kernel, dim3(rowblocks, 2), dim3(256), 0, stream,
                       buf0, Wi + (size_t)5 * HDIM * HDIM, bi + 5 * HDIM,
                       buf2, hi, outi, N);
    x = outi;
  }
}

// Round 2
// 1543.963 us; speedup vs baseline: 10.7053x; 10.7053x over previous
//
#include <hip/hip_runtime.h>
#include <math.h>

#define HDIM 128
#define TM 64
#define TN 64
#define TK 64

// ================= CSR build =================
__global__ __launch_bounds__(256) void degcount_kernel(
    const int* __restrict__ edg, int* __restrict__ deg, int E) {
  int e = blockIdx.x * 256 + threadIdx.x;
  if (e < E) atomicAdd(&deg[edg[E + e]], 1);
}

// single-block chunked exclusive scan: offs[0..n], cursor[i]=offs[i]
__global__ __launch_bounds__(256) void scan_kernel(
    const int* __restrict__ deg, int* __restrict__ offs,
    int* __restrict__ cursor, int n) {
  __shared__ int sums[256];
  const int t = threadIdx.x;
  const int chunk = (n + 255) / 256;
  const int begin = t * chunk;
  const int end = min(begin + chunk, n);
  int s = 0;
  for (int i = begin; i < end; ++i) s += deg[i];
  sums[t] = s;
  __syncthreads();
  for (int off = 1; off < 256; off <<= 1) {
    int add = (t >= off) ? sums[t - off] : 0;
    __syncthreads();
    sums[t] += add;
    __syncthreads();
  }
  int run = sums[t] - s;  // exclusive prefix of this chunk
  for (int i = begin; i < end; ++i) {
    offs[i] = run;
    cursor[i] = run;
    run += deg[i];
  }
  if (t == 0) offs[n] = sums[255];
}

__global__ __launch_bounds__(256) void fill_kernel(
    const int* __restrict__ edg, int* __restrict__ cursor,
    int* __restrict__ csr_src, int E) {
  int e = blockIdx.x * 256 + threadIdx.x;
  if (e < E) {
    int dst = edg[E + e];
    int pos = atomicAdd(&cursor[dst], 1);
    csr_src[pos] = edg[e];
  }
}

// ================= pull aggregation =================
// One wave per node. Lanes 0-31 handle x->A (float4 cols), lanes 32-63 h->Bh.
// A = x + sum_{j in N(i)} x[j] ; Bh = hi + sum hi[j]
__global__ __launch_bounds__(256) void pull2_kernel(
    const int* __restrict__ csr_src, const int* __restrict__ offs,
    const float* __restrict__ x, const float* __restrict__ hi,
    float* __restrict__ A, float* __restrict__ Bh, int N) {
  const int node = blockIdx.x * 4 + (threadIdx.x >> 6);
  if (node >= N) return;
  const int lane = threadIdx.x & 63;
  const int half = lane >> 5;
  const int c = (lane & 31) << 2;
  const float* __restrict__ src = half ? hi : x;
  float* __restrict__ dst = half ? Bh : A;
  const int s = offs[node];
  const int e = offs[node + 1];
  float4 acc = *reinterpret_cast<const float4*>(src + (size_t)node * HDIM + c);
  for (int k = s; k < e; ++k) {
    int j = csr_src[k];
    const float4 v = *reinterpret_cast<const float4*>(src + (size_t)j * HDIM + c);
    acc.x += v.x; acc.y += v.y; acc.z += v.z; acc.w += v.w;
  }
  *reinterpret_cast<float4*>(dst + (size_t)node * HDIM + c) = acc;
}

// One wave per node, single array, float2 per lane.
// Ctot = Corig + sum Corig[j]
__global__ __launch_bounds__(256) void pull1_kernel(
    const int* __restrict__ csr_src, const int* __restrict__ offs,
    const float* __restrict__ Corig, float* __restrict__ Ctot, int N) {
  const int node = blockIdx.x * 4 + (threadIdx.x >> 6);
  if (node >= N) return;
  const int lane = threadIdx.x & 63;
  const int c = lane << 1;
  const int s = offs[node];
  const int e = offs[node + 1];
  float2 acc = *reinterpret_cast<const float2*>(Corig + (size_t)node * HDIM + c);
  for (int k = s; k < e; ++k) {
    int j = csr_src[k];
    const float2 v = *reinterpret_cast<const float2*>(Corig + (size_t)j * HDIM + c);
    acc.x += v.x; acc.y += v.y;
  }
  *reinterpret_cast<float2*>(Ctot + (size_t)node * HDIM + c) = acc;
}

// ================= fused gate GEMM =================
// blockIdx.y = gi in 0..5: group = gi>>1 (0:z, 1:r, 2:h~ partial), half = gi&1
// group 0 -> zpre ; group 1 -> Corig = sigmoid(.)*h_i ; group 2 -> hpre (in outi)
__global__ __launch_bounds__(256) void gemm3_kernel(
    const float* __restrict__ A, const float* __restrict__ Bh,
    const float* __restrict__ W, const float* __restrict__ b,
    const float* __restrict__ hi, float* __restrict__ zpre,
    float* __restrict__ Corig, float* __restrict__ hpre, int N) {
  __shared__ float At[TK * 65];
  __shared__ float Wt[TK * TN];
  const int t = threadIdx.x;
  const int tr = t >> 4;
  const int tc = t & 15;
  const int rowbase = blockIdx.x * TM;
  const int gi = blockIdx.y;
  const int group = gi >> 1;
  const int half = gi & 1;
  const int gate_x = group * 2;
  const int gate_h = group * 2 + 1;
  float acc[4][4] = {{0.f, 0.f, 0.f, 0.f}, {0.f, 0.f, 0.f, 0.f},
                     {0.f, 0.f, 0.f, 0.f}, {0.f, 0.f, 0.f, 0.f}};

  const int nphase = (group < 2) ? 2 : 1;
  for (int phase = 0; phase < nphase; ++phase) {
    const float* __restrict__ src = (phase == 0) ? A : Bh;
    const int gate = (phase == 0) ? gate_x : gate_h;
    const float* __restrict__ wp = W + (size_t)gate * HDIM * HDIM + half * TN;
    for (int kc = 0; kc < HDIM; kc += TK) {
      #pragma unroll
      for (int i = 0; i < 4; ++i) {
        int flat = i * 256 + t;
        int r = flat >> 4;
        int k4 = (flat & 15) << 2;
        int row = rowbase + r;
        float4 v = make_float4(0.f, 0.f, 0.f, 0.f);
        if (row < N)
          v = *reinterpret_cast<const float4*>(src + (size_t)row * HDIM + kc + k4);
        At[(k4 + 0) * 65 + r] = v.x;
        At[(k4 + 1) * 65 + r] = v.y;
        At[(k4 + 2) * 65 + r] = v.z;
        At[(k4 + 3) * 65 + r] = v.w;
      }
      #pragma unroll
      for (int i = 0; i < 4; ++i) {
        int flat = i * 256 + t;
        int k = flat >> 4;
        int c4 = (flat & 15) << 2;
        *reinterpret_cast<float4*>(&Wt[k * TN + c4]) =
            *reinterpret_cast<const float4*>(wp + (size_t)(kc + k) * HDIM + c4);
      }
      __syncthreads();
      #pragma unroll 8
      for (int k = 0; k < TK; ++k) {
        float a0 = At[k * 65 + tr * 4 + 0];
        float a1 = At[k * 65 + tr * 4 + 1];
        float a2 = At[k * 65 + tr * 4 + 2];
        float a3 = At[k * 65 + tr * 4 + 3];
        float4 bv = *reinterpret_cast<const float4*>(&Wt[k * TN + tc * 4]);
        acc[0][0] += a0 * bv.x; acc[0][1] += a0 * bv.y; acc[0][2] += a0 * bv.z; acc[0][3] += a0 * bv.w;
        acc[1][0] += a1 * bv.x; acc[1][1] += a1 * bv.y; acc[1][2] += a1 * bv.z; acc[1][3] += a1 * bv.w;
        acc[2][0] += a2 * bv.x; acc[2][1] += a2 * bv.y; acc[2][2] += a2 * bv.z; acc[2][3] += a2 * bv.w;
        acc[3][0] += a3 * bv.x; acc[3][1] += a3 * bv.y; acc[3][2] += a3 * bv.z; acc[3][3] += a3 * bv.w;
      }
      __syncthreads();
    }
  }

  const int colg = half * TN + tc * 4;
  float bias[4];
  #pragma unroll
  for (int cc = 0; cc < 4; ++cc) {
    float bb = b[gate_x * HDIM + colg + cc];
    if (group < 2) bb += b[gate_h * HDIM + colg + cc];
    bias[cc] = bb;
  }
  #pragma unroll
  for (int rr = 0; rr < 4; ++rr) {
    int row = rowbase + tr * 4 + rr;
    if (row >= N) continue;
    size_t base = (size_t)row * HDIM + colg;
    if (group == 0) {
      #pragma unroll
      for (int cc = 0; cc < 4; ++cc) zpre[base + cc] = acc[rr][cc] + bias[cc];
    } else if (group == 1) {
      #pragma unroll
      for (int cc = 0; cc < 4; ++cc) {
        float v = acc[rr][cc] + bias[cc];
        float r = 1.f / (1.f + expf(-v));
        Corig[base + cc] = r * hi[base + cc];
      }
    } else {
      #pragma unroll
      for (int cc = 0; cc < 4; ++cc) hpre[base + cc] = acc[rr][cc] + bias[cc];
    }
  }
}

// ================= final GEMM + GRU combine =================
__global__ __launch_bounds__(256) void gemm_final_kernel(
    const float* __restrict__ Ctot, const float* __restrict__ W5,
    const float* __restrict__ b5, const float* __restrict__ zpre,
    const float* __restrict__ hi, float* __restrict__ outi, int N) {
  __shared__ float At[TK * 65];
  __shared__ float Wt[TK * TN];
  const int t = threadIdx.x;
  const int tr = t >> 4;
  const int tc = t & 15;
  const int rowbase = blockIdx.x * TM;
  const int half = blockIdx.y;
  const float* __restrict__ wp = W5 + half * TN;
  float acc[4][4] = {{0.f, 0.f, 0.f, 0.f}, {0.f, 0.f, 0.f, 0.f},
                     {0.f, 0.f, 0.f, 0.f}, {0.f, 0.f, 0.f, 0.f}};

  for (int kc = 0; kc < HDIM; kc += TK) {
    #pragma unroll
    for (int i = 0; i < 4; ++i) {
      int flat = i * 256 + t;
      int r = flat >> 4;
      int k4 = (flat & 15) << 2;
      int row = rowbase + r;
      float4 v = make_float4(0.f, 0.f, 0.f, 0.f);
      if (row < N)
        v = *reinterpret_cast<const float4*>(Ctot + (size_t)row * HDIM + kc + k4);
      At[(k4 + 0) * 65 + r] = v.x;
      At[(k4 + 1) * 65 + r] = v.y;
      At[(k4 + 2) * 65 + r] = v.z;
      At[(k4 + 3) * 65 + r] = v.w;
    }
    #pragma unroll
    for (int i = 0; i < 4; ++i) {
      int flat = i * 256 + t;
      int k = flat >> 4;
      int c4 = (flat & 15) << 2;
      *reinterpret_cast<float4*>(&Wt[k * TN + c4]) =
          *reinterpret_cast<const float4*>(wp + (size_t)(kc + k) * HDIM + c4);
    }
    __syncthreads();
    #pragma unroll 8
    for (int k = 0; k < TK; ++k) {
      float a0 = At[k * 65 + tr * 4 + 0];
      float a1 = At[k * 65 + tr * 4 + 1];
      float a2 = At[k * 65 + tr * 4 + 2];
      float a3 = At[k * 65 + tr * 4 + 3];
      float4 bv = *reinterpret_cast<const float4*>(&Wt[k * TN + tc * 4]);
      acc[0][0] += a0 * bv.x; acc[0][1] += a0 * bv.y; acc[0][2] += a0 * bv.z; acc[0][3] += a0 * bv.w;
      acc[1][0] += a1 * bv.x; acc[1][1] += a1 * bv.y; acc[1][2] += a1 * bv.z; acc[1][3] += a1 * bv.w;
      acc[2][0] += a2 * bv.x; acc[2][1] += a2 * bv.y; acc[2][2] += a2 * bv.z; acc[2][3] += a2 * bv.w;
      acc[3][0] += a3 * bv.x; acc[3][1] += a3 * bv.y; acc[3][2] += a3 * bv.z; acc[3][3] += a3 * bv.w;
    }
    __syncthreads();
  }

  const int colg = half * TN + tc * 4;
  #pragma unroll
  for (int rr = 0; rr < 4; ++rr) {
    int row = rowbase + tr * 4 + rr;
    if (row >= N) continue;
    size_t base = (size_t)row * HDIM + colg;
    #pragma unroll
    for (int cc = 0; cc < 4; ++cc) {
      float v = acc[rr][cc] + b5[colg + cc] + outi[base + cc];
      float ht = tanhf(v);
      float z = 1.f / (1.f + expf(-zpre[base + cc]));
      outi[base + cc] = z * hi[base + cc] + (1.f - z) * ht;
    }
  }
}

extern "C" void kernel_launch(void* const* d_in, const int* in_sizes, int n_in,
                              void* d_out, int out_size, void* d_ws, size_t ws_size,
                              hipStream_t stream) {
  const float* inp = (const float*)d_in[0];
  const int*   edg = (const int*)d_in[1];
  const float* h   = (const float*)d_in[2];
  const float* W   = (const float*)d_in[3];
  const float* b   = (const float*)d_in[4];
  float* out = (float*)d_out;

  const int NH = in_sizes[0];      // N*H
  const int N  = NH / HDIM;
  const int E  = in_sizes[1] / 2;
  const int L  = in_sizes[2] / NH;

  float* buf0 = (float*)d_ws;            // A / Ctot
  float* buf1 = buf0 + (size_t)NH;       // Bh
  float* buf2 = buf1 + (size_t)NH;       // zpre
  float* buf3 = buf2 + (size_t)NH;       // Corig
  int* deg     = (int*)(buf3 + (size_t)NH);
  int* offs    = deg + N;                // N+1 entries
  int* cursor  = offs + (N + 1);
  int* csr_src = cursor + N;             // E entries

  const int eblocks = (E + 255) / 256;
  const int nodeblocks = (N + 3) / 4;
  const int rowblocks = (N + TM - 1) / TM;

  // ---- CSR build (once; reused by all aggregations) ----
  hipMemsetAsync(deg, 0, (size_t)N * sizeof(int), stream);
  hipLaunchKernelGGL(degcount_kernel, dim3(eblocks), dim3(256), 0, stream,
                     edg, deg, E);
  hipLaunchKernelGGL(scan_kernel, dim3(1), dim3(256), 0, stream,
                     deg, offs, cursor, N);
  hipLaunchKernelGGL(fill_kernel, dim3(eblocks), dim3(256), 0, stream,
                     edg, cursor, csr_src, E);

  const float* x = inp;
  for (int i = 0; i < L; ++i) {
    const float* hi = h + (size_t)i * NH;
    const float* Wi = W + (size_t)i * 6 * HDIM * HDIM;
    const float* bi = b + (size_t)i * 6 * HDIM;
    float* outi = out + (size_t)i * NH;

    hipLaunchKernelGGL(pull2_kernel, dim3(nodeblocks), dim3(256), 0, stream,
                       csr_src, offs, x, hi, buf0, buf1, N);
    hipLaunchKernelGGL(gemm3_kernel, dim3(rowblocks, 6), dim3(256), 0, stream,
                       buf0, buf1, Wi, bi, hi, buf2, buf3, outi, N);
    hipLaunchKernelGGL(pull1_kernel, dim3(nodeblocks), dim3(256), 0, stream,
                       csr_src, offs, buf3, buf0, N);
    hipLaunchKernelGGL(gemm_final_kernel, dim3(rowblocks, 2), dim3(256), 0, stream,
                       buf0, Wi + (size_t)5 * HDIM * HDIM, bi + 5 * HDIM,
                       buf2, hi, outi, N);
    x = outi;
  }
}

// Round 3
// 1228.694 us; speedup vs baseline: 13.4521x; 1.2566x over previous
//
#include <hip/hip_runtime.h>
#include <math.h>

#define HDIM 128
#define GTM 128
#define GTN 64
#define GTK 64

typedef unsigned short u16;
typedef unsigned int u32;

// ---- bf16 helpers (RNE pack, shift/mask unpack) ----
static __device__ inline u16 f2b(float f) {
  u32 u = __float_as_uint(f);
  u32 r = (u + 0x7FFFu + ((u >> 16) & 1u)) >> 16;
  return (u16)r;
}
static __device__ inline u32 pack2(float a, float b) {
  return (u32)f2b(a) | ((u32)f2b(b) << 16);
}
static __device__ inline float blo(u32 u) { return __uint_as_float(u << 16); }
static __device__ inline float bhi(u32 u) { return __uint_as_float(u & 0xffff0000u); }

// ================= CSR build =================
__global__ __launch_bounds__(256) void degcount_kernel(
    const int* __restrict__ edg, int* __restrict__ deg, int E) {
  int e = blockIdx.x * 256 + threadIdx.x;
  if (e < E) atomicAdd(&deg[edg[E + e]], 1);
}

__global__ __launch_bounds__(256) void scan_kernel(
    const int* __restrict__ deg, int* __restrict__ offs,
    int* __restrict__ cursor, int n) {
  __shared__ int sums[256];
  const int t = threadIdx.x;
  const int chunk = (n + 255) / 256;
  const int begin = t * chunk;
  const int end = min(begin + chunk, n);
  int s = 0;
  for (int i = begin; i < end; ++i) s += deg[i];
  sums[t] = s;
  __syncthreads();
  for (int off = 1; off < 256; off <<= 1) {
    int add = (t >= off) ? sums[t - off] : 0;
    __syncthreads();
    sums[t] += add;
    __syncthreads();
  }
  int run = sums[t] - s;
  for (int i = begin; i < end; ++i) {
    offs[i] = run;
    cursor[i] = run;
    run += deg[i];
  }
  if (t == 0) offs[n] = sums[255];
}

__global__ __launch_bounds__(256) void fill_kernel(
    const int* __restrict__ edg, int* __restrict__ cursor,
    int* __restrict__ csr_src, int E) {
  int e = blockIdx.x * 256 + threadIdx.x;
  if (e < E) {
    int dst = edg[E + e];
    int pos = atomicAdd(&cursor[dst], 1);
    csr_src[pos] = edg[e];
  }
}

// ================= fp32 -> bf16 conversion =================
__global__ __launch_bounds__(256) void conv_kernel(
    const float* __restrict__ s, u16* __restrict__ d, int n4) {
  int i = blockIdx.x * 256 + threadIdx.x;
  if (i < n4) {
    float4 v = reinterpret_cast<const float4*>(s)[i];
    uint2 o;
    o.x = pack2(v.x, v.y);
    o.y = pack2(v.z, v.w);
    reinterpret_cast<uint2*>(d)[i] = o;
  }
}

// ================= pull aggregation (bf16 gather, fp32 accumulate) ======
// One wave per node. Lanes 0-31: x, lanes 32-63: h. 4 cols/lane (8 B bf16).
__global__ __launch_bounds__(256) void pull2_kernel(
    const int* __restrict__ csr_src, const int* __restrict__ offs,
    const float* __restrict__ xf, const float* __restrict__ hf,
    const u16* __restrict__ xb, const u16* __restrict__ hb,
    float* __restrict__ A, float* __restrict__ Bh, int N) {
  const int node = blockIdx.x * 4 + (threadIdx.x >> 6);
  if (node >= N) return;
  const int lane = threadIdx.x & 63;
  const int half = lane >> 5;
  const int c = (lane & 31) << 2;
  const float* __restrict__ selfp = half ? hf : xf;
  const u16* __restrict__ nb = half ? hb : xb;
  float* __restrict__ dst = half ? Bh : A;
  const int s = offs[node];
  const int e = offs[node + 1];
  float4 acc = *reinterpret_cast<const float4*>(selfp + (size_t)node * HDIM + c);
  int k = s;
  for (; k + 2 <= e; k += 2) {
    int j0 = csr_src[k];
    int j1 = csr_src[k + 1];
    uint2 u0 = *reinterpret_cast<const uint2*>(nb + (size_t)j0 * HDIM + c);
    uint2 u1 = *reinterpret_cast<const uint2*>(nb + (size_t)j1 * HDIM + c);
    acc.x += blo(u0.x) + blo(u1.x);
    acc.y += bhi(u0.x) + bhi(u1.x);
    acc.z += blo(u0.y) + blo(u1.y);
    acc.w += bhi(u0.y) + bhi(u1.y);
  }
  if (k < e) {
    int j0 = csr_src[k];
    uint2 u0 = *reinterpret_cast<const uint2*>(nb + (size_t)j0 * HDIM + c);
    acc.x += blo(u0.x);
    acc.y += bhi(u0.x);
    acc.z += blo(u0.y);
    acc.w += bhi(u0.y);
  }
  *reinterpret_cast<float4*>(dst + (size_t)node * HDIM + c) = acc;
}

// One wave per node, single bf16 array, 2 cols/lane (4 B).
__global__ __launch_bounds__(256) void pull1_kernel(
    const int* __restrict__ csr_src, const int* __restrict__ offs,
    const u16* __restrict__ cb, float* __restrict__ Ctot, int N) {
  const int node = blockIdx.x * 4 + (threadIdx.x >> 6);
  if (node >= N) return;
  const int lane = threadIdx.x & 63;
  const int c = lane << 1;
  const int s = offs[node];
  const int e = offs[node + 1];
  u32 us = *reinterpret_cast<const u32*>(cb + (size_t)node * HDIM + c);
  float2 acc = make_float2(blo(us), bhi(us));
  int k = s;
  for (; k + 2 <= e; k += 2) {
    int j0 = csr_src[k];
    int j1 = csr_src[k + 1];
    u32 u0 = *reinterpret_cast<const u32*>(cb + (size_t)j0 * HDIM + c);
    u32 u1 = *reinterpret_cast<const u32*>(cb + (size_t)j1 * HDIM + c);
    acc.x += blo(u0) + blo(u1);
    acc.y += bhi(u0) + bhi(u1);
  }
  if (k < e) {
    u32 u0 = *reinterpret_cast<const u32*>(cb + (size_t)csr_src[k] * HDIM + c);
    acc.x += blo(u0);
    acc.y += bhi(u0);
  }
  *reinterpret_cast<float2*>(Ctot + (size_t)node * HDIM + c) = acc;
}

// ================= fused gate GEMM (fp32, 128x64 tile, 4x8/thread) ======
// blockIdx.y = gi in 0..5: group = gi>>1 (0:z, 1:r, 2:h~ partial), half = gi&1
// group 0 -> zb (bf16 zpre) ; group 1 -> cb = bf16(sigmoid(.)*h_i) ;
// group 2 -> hpre (fp32, stored in outi)
__global__ __launch_bounds__(256) void gemm3_kernel(
    const float* __restrict__ A, const float* __restrict__ Bh,
    const float* __restrict__ W, const float* __restrict__ b,
    const float* __restrict__ hi, u16* __restrict__ zb,
    u16* __restrict__ cb, float* __restrict__ hpre, int N) {
  __shared__ float As[GTM * 65];
  __shared__ float Wt[GTK * GTN];
  const int t = threadIdx.x;
  const int tr = t >> 3;   // 0..31 -> rows tr*4..tr*4+3
  const int tc = t & 7;    // 0..7  -> cols tc*8..tc*8+7
  const int rowbase = blockIdx.x * GTM;
  const int gi = blockIdx.y;
  const int group = gi >> 1;
  const int half = gi & 1;
  float acc[4][8];
  #pragma unroll
  for (int i = 0; i < 4; ++i)
    #pragma unroll
    for (int j = 0; j < 8; ++j) acc[i][j] = 0.f;

  const int nphase = (group < 2) ? 2 : 1;
  for (int phase = 0; phase < nphase; ++phase) {
    const float* __restrict__ src = phase ? Bh : A;
    const int gate = group * 2 + phase;
    const float* __restrict__ wp = W + (size_t)gate * HDIM * HDIM + half * GTN;
    for (int kc = 0; kc < HDIM; kc += GTK) {
      #pragma unroll
      for (int i = 0; i < 8; ++i) {
        int flat = i * 256 + t;
        int r = flat >> 4;            // 0..127
        int c4 = (flat & 15) << 2;    // 0..60
        int row = rowbase + r;
        float4 v = make_float4(0.f, 0.f, 0.f, 0.f);
        if (row < N)
          v = *reinterpret_cast<const float4*>(src + (size_t)row * HDIM + kc + c4);
        As[r * 65 + c4 + 0] = v.x;
        As[r * 65 + c4 + 1] = v.y;
        As[r * 65 + c4 + 2] = v.z;
        As[r * 65 + c4 + 3] = v.w;
      }
      #pragma unroll
      for (int i = 0; i < 4; ++i) {
        int flat = i * 256 + t;
        int k = flat >> 4;            // 0..63
        int c4 = (flat & 15) << 2;
        *reinterpret_cast<float4*>(&Wt[k * GTN + c4]) =
            *reinterpret_cast<const float4*>(wp + (size_t)(kc + k) * HDIM + c4);
      }
      __syncthreads();
      #pragma unroll 8
      for (int k = 0; k < GTK; ++k) {
        float a0 = As[(tr * 4 + 0) * 65 + k];
        float a1 = As[(tr * 4 + 1) * 65 + k];
        float a2 = As[(tr * 4 + 2) * 65 + k];
        float a3 = As[(tr * 4 + 3) * 65 + k];
        float4 w0 = *reinterpret_cast<const float4*>(&Wt[k * GTN + tc * 8]);
        float4 w1 = *reinterpret_cast<const float4*>(&Wt[k * GTN + tc * 8 + 4]);
        acc[0][0] += a0 * w0.x; acc[0][1] += a0 * w0.y; acc[0][2] += a0 * w0.z; acc[0][3] += a0 * w0.w;
        acc[0][4] += a0 * w1.x; acc[0][5] += a0 * w1.y; acc[0][6] += a0 * w1.z; acc[0][7] += a0 * w1.w;
        acc[1][0] += a1 * w0.x; acc[1][1] += a1 * w0.y; acc[1][2] += a1 * w0.z; acc[1][3] += a1 * w0.w;
        acc[1][4] += a1 * w1.x; acc[1][5] += a1 * w1.y; acc[1][6] += a1 * w1.z; acc[1][7] += a1 * w1.w;
        acc[2][0] += a2 * w0.x; acc[2][1] += a2 * w0.y; acc[2][2] += a2 * w0.z; acc[2][3] += a2 * w0.w;
        acc[2][4] += a2 * w1.x; acc[2][5] += a2 * w1.y; acc[2][6] += a2 * w1.z; acc[2][7] += a2 * w1.w;
        acc[3][0] += a3 * w0.x; acc[3][1] += a3 * w0.y; acc[3][2] += a3 * w0.z; acc[3][3] += a3 * w0.w;
        acc[3][4] += a3 * w1.x; acc[3][5] += a3 * w1.y; acc[3][6] += a3 * w1.z; acc[3][7] += a3 * w1.w;
      }
      __syncthreads();
    }
  }

  const int colg = half * GTN + tc * 8;
  float bias[8];
  #pragma unroll
  for (int cc = 0; cc < 8; ++cc) {
    float bb = b[(group * 2) * HDIM + colg + cc];
    if (group < 2) bb += b[(group * 2 + 1) * HDIM + colg + cc];
    bias[cc] = bb;
  }
  #pragma unroll
  for (int rr = 0; rr < 4; ++rr) {
    int row = rowbase + tr * 4 + rr;
    if (row >= N) continue;
    size_t base = (size_t)row * HDIM + colg;
    float v[8];
    #pragma unroll
    for (int cc = 0; cc < 8; ++cc) v[cc] = acc[rr][cc] + bias[cc];
    if (group == 0) {
      uint2 p0, p1;
      p0.x = pack2(v[0], v[1]); p0.y = pack2(v[2], v[3]);
      p1.x = pack2(v[4], v[5]); p1.y = pack2(v[6], v[7]);
      *reinterpret_cast<uint2*>(zb + base) = p0;
      *reinterpret_cast<uint2*>(zb + base + 4) = p1;
    } else if (group == 1) {
      float4 h0 = *reinterpret_cast<const float4*>(hi + base);
      float4 h1 = *reinterpret_cast<const float4*>(hi + base + 4);
      float r0 = (1.f / (1.f + expf(-v[0]))) * h0.x;
      float r1 = (1.f / (1.f + expf(-v[1]))) * h0.y;
      float r2 = (1.f / (1.f + expf(-v[2]))) * h0.z;
      float r3 = (1.f / (1.f + expf(-v[3]))) * h0.w;
      float r4 = (1.f / (1.f + expf(-v[4]))) * h1.x;
      float r5 = (1.f / (1.f + expf(-v[5]))) * h1.y;
      float r6 = (1.f / (1.f + expf(-v[6]))) * h1.z;
      float r7 = (1.f / (1.f + expf(-v[7]))) * h1.w;
      uint2 p0, p1;
      p0.x = pack2(r0, r1); p0.y = pack2(r2, r3);
      p1.x = pack2(r4, r5); p1.y = pack2(r6, r7);
      *reinterpret_cast<uint2*>(cb + base) = p0;
      *reinterpret_cast<uint2*>(cb + base + 4) = p1;
    } else {
      *reinterpret_cast<float4*>(hpre + base) = make_float4(v[0], v[1], v[2], v[3]);
      *reinterpret_cast<float4*>(hpre + base + 4) = make_float4(v[4], v[5], v[6], v[7]);
    }
  }
}

// ================= final GEMM + GRU combine =================
// acc = Ctot @ W5 ; v = acc + b5 + hpre(outi); h~ = tanh(v);
// z = sigmoid(zpre); out = z*h + (1-z)*h~ ; also write bf16 copy (next x)
__global__ __launch_bounds__(256) void gemm_final_kernel(
    const float* __restrict__ Ctot, const float* __restrict__ W5,
    const float* __restrict__ b5, const u16* __restrict__ zb,
    const float* __restrict__ hi, float* __restrict__ outi,
    u16* __restrict__ xb, int N) {
  __shared__ float As[GTM * 65];
  __shared__ float Wt[GTK * GTN];
  const int t = threadIdx.x;
  const int tr = t >> 3;
  const int tc = t & 7;
  const int rowbase = blockIdx.x * GTM;
  const int half = blockIdx.y;
  const float* __restrict__ wp = W5 + half * GTN;
  float acc[4][8];
  #pragma unroll
  for (int i = 0; i < 4; ++i)
    #pragma unroll
    for (int j = 0; j < 8; ++j) acc[i][j] = 0.f;

  for (int kc = 0; kc < HDIM; kc += GTK) {
    #pragma unroll
    for (int i = 0; i < 8; ++i) {
      int flat = i * 256 + t;
      int r = flat >> 4;
      int c4 = (flat & 15) << 2;
      int row = rowbase + r;
      float4 v = make_float4(0.f, 0.f, 0.f, 0.f);
      if (row < N)
        v = *reinterpret_cast<const float4*>(Ctot + (size_t)row * HDIM + kc + c4);
      As[r * 65 + c4 + 0] = v.x;
      As[r * 65 + c4 + 1] = v.y;
      As[r * 65 + c4 + 2] = v.z;
      As[r * 65 + c4 + 3] = v.w;
    }
    #pragma unroll
    for (int i = 0; i < 4; ++i) {
      int flat = i * 256 + t;
      int k = flat >> 4;
      int c4 = (flat & 15) << 2;
      *reinterpret_cast<float4*>(&Wt[k * GTN + c4]) =
          *reinterpret_cast<const float4*>(wp + (size_t)(kc + k) * HDIM + c4);
    }
    __syncthreads();
    #pragma unroll 8
    for (int k = 0; k < GTK; ++k) {
      float a0 = As[(tr * 4 + 0) * 65 + k];
      float a1 = As[(tr * 4 + 1) * 65 + k];
      float a2 = As[(tr * 4 + 2) * 65 + k];
      float a3 = As[(tr * 4 + 3) * 65 + k];
      float4 w0 = *reinterpret_cast<const float4*>(&Wt[k * GTN + tc * 8]);
      float4 w1 = *reinterpret_cast<const float4*>(&Wt[k * GTN + tc * 8 + 4]);
      acc[0][0] += a0 * w0.x; acc[0][1] += a0 * w0.y; acc[0][2] += a0 * w0.z; acc[0][3] += a0 * w0.w;
      acc[0][4] += a0 * w1.x; acc[0][5] += a0 * w1.y; acc[0][6] += a0 * w1.z; acc[0][7] += a0 * w1.w;
      acc[1][0] += a1 * w0.x; acc[1][1] += a1 * w0.y; acc[1][2] += a1 * w0.z; acc[1][3] += a1 * w0.w;
      acc[1][4] += a1 * w1.x; acc[1][5] += a1 * w1.y; acc[1][6] += a1 * w1.z; acc[1][7] += a1 * w1.w;
      acc[2][0] += a2 * w0.x; acc[2][1] += a2 * w0.y; acc[2][2] += a2 * w0.z; acc[2][3] += a2 * w0.w;
      acc[2][4] += a2 * w1.x; acc[2][5] += a2 * w1.y; acc[2][6] += a2 * w1.z; acc[2][7] += a2 * w1.w;
      acc[3][0] += a3 * w0.x; acc[3][1] += a3 * w0.y; acc[3][2] += a3 * w0.z; acc[3][3] += a3 * w0.w;
      acc[3][4] += a3 * w1.x; acc[3][5] += a3 * w1.y; acc[3][6] += a3 * w1.z; acc[3][7] += a3 * w1.w;
    }
    __syncthreads();
  }

  const int colg = half * GTN + tc * 8;
  #pragma unroll
  for (int rr = 0; rr < 4; ++rr) {
    int row = rowbase + tr * 4 + rr;
    if (row >= N) continue;
    size_t base = (size_t)row * HDIM + colg;
    float4 hp0 = *reinterpret_cast<const float4*>(outi + base);
    float4 hp1 = *reinterpret_cast<const float4*>(outi + base + 4);
    float4 h0 = *reinterpret_cast<const float4*>(hi + base);
    float4 h1 = *reinterpret_cast<const float4*>(hi + base + 4);
    uint2 z01 = *reinterpret_cast<const uint2*>(zb + base);
    uint2 z23 = *reinterpret_cast<const uint2*>(zb + base + 4);
    float hpv[8] = {hp0.x, hp0.y, hp0.z, hp0.w, hp1.x, hp1.y, hp1.z, hp1.w};
    float hv[8]  = {h0.x, h0.y, h0.z, h0.w, h1.x, h1.y, h1.z, h1.w};
    float zv[8]  = {blo(z01.x), bhi(z01.x), blo(z01.y), bhi(z01.y),
                    blo(z23.x), bhi(z23.x), blo(z23.y), bhi(z23.y)};
    float o[8];
    #pragma unroll
    for (int cc = 0; cc < 8; ++cc) {
      float v = acc[rr][cc] + b5[colg + cc] + hpv[cc];
      float ht = tanhf(v);
      float z = 1.f / (1.f + expf(-zv[cc]));
      o[cc] = z * hv[cc] + (1.f - z) * ht;
    }
    *reinterpret_cast<float4*>(outi + base)     = make_float4(o[0], o[1], o[2], o[3]);
    *reinterpret_cast<float4*>(outi + base + 4) = make_float4(o[4], o[5], o[6], o[7]);
    uint2 p0, p1;
    p0.x = pack2(o[0], o[1]); p0.y = pack2(o[2], o[3]);
    p1.x = pack2(o[4], o[5]); p1.y = pack2(o[6], o[7]);
    *reinterpret_cast<uint2*>(xb + base)     = p0;
    *reinterpret_cast<uint2*>(xb + base + 4) = p1;
  }
}

extern "C" void kernel_launch(void* const* d_in, const int* in_sizes, int n_in,
                              void* d_out, int out_size, void* d_ws, size_t ws_size,
                              hipStream_t stream) {
  const float* inp = (const float*)d_in[0];
  const int*   edg = (const int*)d_in[1];
  const float* h   = (const float*)d_in[2];
  const float* W   = (const float*)d_in[3];
  const float* b   = (const float*)d_in[4];
  float* out = (float*)d_out;

  const int NH = in_sizes[0];      // N*H
  const int N  = NH / HDIM;
  const int E  = in_sizes[1] / 2;
  const int L  = in_sizes[2] / NH;

  float* buf0 = (float*)d_ws;            // A / Ctot (fp32)
  float* buf1 = buf0 + (size_t)NH;       // Bh (fp32)
  u16* zb = (u16*)(buf1 + (size_t)NH);   // zpre bf16
  u16* cb = zb + (size_t)NH;             // Corig bf16
  u16* xb = cb + (size_t)NH;             // x bf16
  u16* hb = xb + (size_t)NH;             // h_i bf16
  int* deg     = (int*)(hb + (size_t)NH);
  int* offs    = deg + N;                // N+1 entries
  int* cursor  = offs + (N + 1);
  int* csr_src = cursor + N;             // E entries

  const int eblocks = (E + 255) / 256;
  const int nodeblocks = (N + 3) / 4;
  const int n4 = NH / 4;
  const int cvblocks = (n4 + 255) / 256;
  const int rowblocks = (N + GTM - 1) / GTM;

  // ---- CSR build (once; reused by all aggregations) ----
  hipMemsetAsync(deg, 0, (size_t)N * sizeof(int), stream);
  hipLaunchKernelGGL(degcount_kernel, dim3(eblocks), dim3(256), 0, stream,
                     edg, deg, E);
  hipLaunchKernelGGL(scan_kernel, dim3(1), dim3(256), 0, stream,
                     deg, offs, cursor, N);
  hipLaunchKernelGGL(fill_kernel, dim3(eblocks), dim3(256), 0, stream,
                     edg, cursor, csr_src, E);
  hipLaunchKernelGGL(conv_kernel, dim3(cvblocks), dim3(256), 0, stream,
                     inp, xb, n4);

  const float* x = inp;
  for (int i = 0; i < L; ++i) {
    const float* hi = h + (size_t)i * NH;
    const float* Wi = W + (size_t)i * 6 * HDIM * HDIM;
    const float* bi = b + (size_t)i * 6 * HDIM;
    float* outi = out + (size_t)i * NH;

    hipLaunchKernelGGL(conv_kernel, dim3(cvblocks), dim3(256), 0, stream,
                       hi, hb, n4);
    hipLaunchKernelGGL(pull2_kernel, dim3(nodeblocks), dim3(256), 0, stream,
                       csr_src, offs, x, hi, xb, hb, buf0, buf1, N);
    hipLaunchKernelGGL(gemm3_kernel, dim3(rowblocks, 6), dim3(256), 0, stream,
                       buf0, buf1, Wi, bi, hi, zb, cb, outi, N);
    hipLaunchKernelGGL(pull1_kernel, dim3(nodeblocks), dim3(256), 0, stream,
                       csr_src, offs, cb, buf0, N);
    // gemm_final also writes xb = bf16(out) for the next layer's pull
    hipLaunchKernelGGL(gemm_final_kernel, dim3(rowblocks, 2), dim3(256), 0, stream,
                       buf0, Wi + (size_t)5 * HDIM * HDIM, bi + 5 * HDIM,
                       zb, hi, outi, xb, N);
    x = outi;
  }
}

// Round 4
// 1021.437 us; speedup vs baseline: 16.1816x; 1.2029x over previous
//
#include <hip/hip_runtime.h>
#include <math.h>

#define HDIM 128
#define GTM 128   // rows per block
#define GTK 32    // k chunk
#define ASTRIDE 132  // k-major A tile stride (16B-aligned b128 reads, conflict-free)

typedef unsigned short u16;
typedef unsigned int u32;
typedef _Float16 f16;
typedef __attribute__((ext_vector_type(2))) _Float16 f16x2;
typedef __attribute__((ext_vector_type(4))) _Float16 f16x4;
typedef __attribute__((ext_vector_type(8))) _Float16 f16x8;

// ================= CSR build =================
__global__ __launch_bounds__(256) void degcount_kernel(
    const int* __restrict__ edg, int* __restrict__ deg, int E) {
  int e = blockIdx.x * 256 + threadIdx.x;
  if (e < E) atomicAdd(&deg[edg[E + e]], 1);
}

// phase 1: per-block partial sums of deg over contiguous chunks
__global__ __launch_bounds__(256) void scan_part_kernel(
    const int* __restrict__ deg, int* __restrict__ bsum, int n, int chunk) {
  __shared__ int red[256];
  const int b = blockIdx.x, t = threadIdx.x;
  const int begin = b * chunk;
  const int end = min(begin + chunk, n);
  int s = 0;
  for (int i = begin + t; i < end; i += 256) s += deg[i];
  red[t] = s;
  __syncthreads();
  for (int off = 128; off > 0; off >>= 1) {
    if (t < off) red[t] += red[t + off];
    __syncthreads();
  }
  if (t == 0) bsum[b] = red[0];
}

// phase 2: exclusive scan of 256 block sums (1 block); also writes offs[n]
__global__ __launch_bounds__(256) void scan_top_kernel(
    const int* __restrict__ bsum, int* __restrict__ boff,
    int* __restrict__ offs, int n) {
  __shared__ int sh[256];
  const int t = threadIdx.x;
  int v = bsum[t];
  sh[t] = v;
  __syncthreads();
  for (int off = 1; off < 256; off <<= 1) {
    int add = (t >= off) ? sh[t - off] : 0;
    __syncthreads();
    sh[t] += add;
    __syncthreads();
  }
  boff[t] = sh[t] - v;  // exclusive prefix
  if (t == 255) offs[n] = sh[255];
}

// phase 3: per-block scan of its chunk (chunk <= 256 required; N<=65536)
__global__ __launch_bounds__(256) void scan_fin_kernel(
    const int* __restrict__ deg, const int* __restrict__ boff,
    int* __restrict__ offs, int* __restrict__ cursor, int n, int chunk) {
  __shared__ int sh[256];
  const int b = blockIdx.x, t = threadIdx.x;
  const int idx = b * chunk + t;
  int v = (t < chunk && idx < n) ? deg[idx] : 0;
  sh[t] = v;
  __syncthreads();
  for (int off = 1; off < 256; off <<= 1) {
    int add = (t >= off) ? sh[t - off] : 0;
    __syncthreads();
    sh[t] += add;
    __syncthreads();
  }
  if (t < chunk && idx < n) {
    int o = boff[b] + sh[t] - v;
    offs[idx] = o;
    cursor[idx] = o;
  }
}

__global__ __launch_bounds__(256) void fill_kernel(
    const int* __restrict__ edg, int* __restrict__ cursor,
    int* __restrict__ csr_src, int E) {
  int e = blockIdx.x * 256 + threadIdx.x;
  if (e < E) {
    int dst = edg[E + e];
    int pos = atomicAdd(&cursor[dst], 1);
    csr_src[pos] = edg[e];
  }
}

// ================= fp32 -> fp16 conversion =================
__global__ __launch_bounds__(256) void convh_kernel(
    const float* __restrict__ s, f16* __restrict__ d, int n4) {
  int i = blockIdx.x * 256 + threadIdx.x;
  if (i < n4) {
    float4 v = reinterpret_cast<const float4*>(s)[i];
    f16x4 o;
    o[0] = (f16)v.x; o[1] = (f16)v.y; o[2] = (f16)v.z; o[3] = (f16)v.w;
    reinterpret_cast<f16x4*>(d)[i] = o;
  }
}

// ================= pull aggregation (fp16 gather, fp32 accumulate) ======
// One wave per node. Lanes 0-31: x, lanes 32-63: h. 4 cols/lane (8 B fp16).
__global__ __launch_bounds__(256) void pull2_kernel(
    const int* __restrict__ csr_src, const int* __restrict__ offs,
    const float* __restrict__ xf, const float* __restrict__ hf,
    const f16* __restrict__ xb, const f16* __restrict__ hb,
    float* __restrict__ A, float* __restrict__ Bh, int N) {
  const int node = blockIdx.x * 4 + (threadIdx.x >> 6);
  if (node >= N) return;
  const int lane = threadIdx.x & 63;
  const int half = lane >> 5;
  const int c = (lane & 31) << 2;
  const float* __restrict__ selfp = half ? hf : xf;
  const f16* __restrict__ nb = half ? hb : xb;
  float* __restrict__ dst = half ? Bh : A;
  const int s = offs[node];
  const int e = offs[node + 1];
  float4 acc = *reinterpret_cast<const float4*>(selfp + (size_t)node * HDIM + c);
  int k = s;
  for (; k + 4 <= e; k += 4) {
    int j0 = csr_src[k];
    int j1 = csr_src[k + 1];
    int j2 = csr_src[k + 2];
    int j3 = csr_src[k + 3];
    f16x4 u0 = *reinterpret_cast<const f16x4*>(nb + (size_t)j0 * HDIM + c);
    f16x4 u1 = *reinterpret_cast<const f16x4*>(nb + (size_t)j1 * HDIM + c);
    f16x4 u2 = *reinterpret_cast<const f16x4*>(nb + (size_t)j2 * HDIM + c);
    f16x4 u3 = *reinterpret_cast<const f16x4*>(nb + (size_t)j3 * HDIM + c);
    acc.x += (float)u0[0] + (float)u1[0] + (float)u2[0] + (float)u3[0];
    acc.y += (float)u0[1] + (float)u1[1] + (float)u2[1] + (float)u3[1];
    acc.z += (float)u0[2] + (float)u1[2] + (float)u2[2] + (float)u3[2];
    acc.w += (float)u0[3] + (float)u1[3] + (float)u2[3] + (float)u3[3];
  }
  for (; k < e; ++k) {
    f16x4 u0 = *reinterpret_cast<const f16x4*>(nb + (size_t)csr_src[k] * HDIM + c);
    acc.x += (float)u0[0];
    acc.y += (float)u0[1];
    acc.z += (float)u0[2];
    acc.w += (float)u0[3];
  }
  *reinterpret_cast<float4*>(dst + (size_t)node * HDIM + c) = acc;
}

// One wave per node, single fp16 array, 2 cols/lane (4 B).
__global__ __launch_bounds__(256) void pull1_kernel(
    const int* __restrict__ csr_src, const int* __restrict__ offs,
    const f16* __restrict__ cb, float* __restrict__ Ctot, int N) {
  const int node = blockIdx.x * 4 + (threadIdx.x >> 6);
  if (node >= N) return;
  const int lane = threadIdx.x & 63;
  const int c = lane << 1;
  const int s = offs[node];
  const int e = offs[node + 1];
  f16x2 us = *reinterpret_cast<const f16x2*>(cb + (size_t)node * HDIM + c);
  float2 acc = make_float2((float)us[0], (float)us[1]);
  int k = s;
  for (; k + 4 <= e; k += 4) {
    int j0 = csr_src[k];
    int j1 = csr_src[k + 1];
    int j2 = csr_src[k + 2];
    int j3 = csr_src[k + 3];
    f16x2 u0 = *reinterpret_cast<const f16x2*>(cb + (size_t)j0 * HDIM + c);
    f16x2 u1 = *reinterpret_cast<const f16x2*>(cb + (size_t)j1 * HDIM + c);
    f16x2 u2 = *reinterpret_cast<const f16x2*>(cb + (size_t)j2 * HDIM + c);
    f16x2 u3 = *reinterpret_cast<const f16x2*>(cb + (size_t)j3 * HDIM + c);
    acc.x += (float)u0[0] + (float)u1[0] + (float)u2[0] + (float)u3[0];
    acc.y += (float)u0[1] + (float)u1[1] + (float)u2[1] + (float)u3[1];
  }
  for (; k < e; ++k) {
    f16x2 u0 = *reinterpret_cast<const f16x2*>(cb + (size_t)csr_src[k] * HDIM + c);
    acc.x += (float)u0[0];
    acc.y += (float)u0[1];
  }
  *reinterpret_cast<float2*>(Ctot + (size_t)node * HDIM + c) = acc;
}

// ================= fused gate GEMM (fp32, 128x128 tile, 8x8/thread) ======
// blockIdx.y = group: 0 -> zpre (f16) ; 1 -> cb = f16(sigmoid(.)*h_i) ;
// 2 -> hpre (fp32, stored in outi)
__global__ __launch_bounds__(256, 4) void gemm3_kernel(
    const float* __restrict__ A, const float* __restrict__ Bh,
    const float* __restrict__ W, const float* __restrict__ b,
    const float* __restrict__ hi, f16* __restrict__ zb,
    f16* __restrict__ cb, float* __restrict__ hpre, int N) {
  __shared__ float As[GTK * ASTRIDE];   // k-major: As[k][row]
  __shared__ float Ws[GTK * HDIM];      // k-major: Ws[k][col]
  const int t = threadIdx.x;
  const int tr = t >> 4;   // 0..15 -> rows tr*8..+7
  const int tc = t & 15;   // 0..15 -> cols tc*8..+7
  const int rowbase = blockIdx.x * GTM;
  const int group = blockIdx.y;
  float acc[8][8];
  #pragma unroll
  for (int i = 0; i < 8; ++i)
    #pragma unroll
    for (int j = 0; j < 8; ++j) acc[i][j] = 0.f;

  const int nphase = (group < 2) ? 2 : 1;
  for (int phase = 0; phase < nphase; ++phase) {
    const float* __restrict__ src = phase ? Bh : A;
    const int gate = group * 2 + phase;
    const float* __restrict__ wp = W + (size_t)gate * HDIM * HDIM;
    for (int kc = 0; kc < HDIM; kc += GTK) {
      // stage A tile transposed: As[k][r]
      #pragma unroll
      for (int i = 0; i < 4; ++i) {
        int flat = i * 256 + t;
        int r = flat >> 3;            // 0..127
        int c4 = (flat & 7) << 2;     // 0..28
        int row = rowbase + r;
        float4 v = make_float4(0.f, 0.f, 0.f, 0.f);
        if (row < N)
          v = *reinterpret_cast<const float4*>(src + (size_t)row * HDIM + kc + c4);
        As[(c4 + 0) * ASTRIDE + r] = v.x;
        As[(c4 + 1) * ASTRIDE + r] = v.y;
        As[(c4 + 2) * ASTRIDE + r] = v.z;
        As[(c4 + 3) * ASTRIDE + r] = v.w;
      }
      // stage W tile: Ws[k][c]
      #pragma unroll
      for (int i = 0; i < 4; ++i) {
        int flat = i * 256 + t;
        int k = flat >> 5;            // 0..31
        int c4 = (flat & 31) << 2;    // 0..124
        *reinterpret_cast<float4*>(&Ws[k * HDIM + c4]) =
            *reinterpret_cast<const float4*>(wp + (size_t)(kc + k) * HDIM + c4);
      }
      __syncthreads();
      #pragma unroll 4
      for (int k = 0; k < GTK; ++k) {
        float4 a0 = *reinterpret_cast<const float4*>(&As[k * ASTRIDE + tr * 8]);
        float4 a1 = *reinterpret_cast<const float4*>(&As[k * ASTRIDE + tr * 8 + 4]);
        float4 w0 = *reinterpret_cast<const float4*>(&Ws[k * HDIM + tc * 8]);
        float4 w1 = *reinterpret_cast<const float4*>(&Ws[k * HDIM + tc * 8 + 4]);
        float av[8] = {a0.x, a0.y, a0.z, a0.w, a1.x, a1.y, a1.z, a1.w};
        float wv[8] = {w0.x, w0.y, w0.z, w0.w, w1.x, w1.y, w1.z, w1.w};
        #pragma unroll
        for (int i = 0; i < 8; ++i)
          #pragma unroll
          for (int j = 0; j < 8; ++j) acc[i][j] += av[i] * wv[j];
      }
      __syncthreads();
    }
  }

  const int col = tc * 8;
  float bias[8];
  #pragma unroll
  for (int cc = 0; cc < 8; ++cc) {
    float bb = b[(group * 2) * HDIM + col + cc];
    if (group < 2) bb += b[(group * 2 + 1) * HDIM + col + cc];
    bias[cc] = bb;
  }
  #pragma unroll
  for (int rr = 0; rr < 8; ++rr) {
    int row = rowbase + tr * 8 + rr;
    if (row >= N) continue;
    size_t base = (size_t)row * HDIM + col;
    float v[8];
    #pragma unroll
    for (int cc = 0; cc < 8; ++cc) v[cc] = acc[rr][cc] + bias[cc];
    if (group == 0) {
      f16x8 o;
      #pragma unroll
      for (int cc = 0; cc < 8; ++cc) o[cc] = (f16)v[cc];
      *reinterpret_cast<f16x8*>(zb + base) = o;
    } else if (group == 1) {
      float4 h0 = *reinterpret_cast<const float4*>(hi + base);
      float4 h1 = *reinterpret_cast<const float4*>(hi + base + 4);
      float hv[8] = {h0.x, h0.y, h0.z, h0.w, h1.x, h1.y, h1.z, h1.w};
      f16x8 o;
      #pragma unroll
      for (int cc = 0; cc < 8; ++cc) {
        float r = 1.f / (1.f + expf(-v[cc]));
        o[cc] = (f16)(r * hv[cc]);
      }
      *reinterpret_cast<f16x8*>(cb + base) = o;
    } else {
      *reinterpret_cast<float4*>(hpre + base) = make_float4(v[0], v[1], v[2], v[3]);
      *reinterpret_cast<float4*>(hpre + base + 4) = make_float4(v[4], v[5], v[6], v[7]);
    }
  }
}

// ================= final GEMM + GRU combine =================
__global__ __launch_bounds__(256, 4) void gemm_final_kernel(
    const float* __restrict__ Ctot, const float* __restrict__ W5,
    const float* __restrict__ b5, const f16* __restrict__ zb,
    const float* __restrict__ hi, float* __restrict__ outi,
    f16* __restrict__ xb, int N) {
  __shared__ float As[GTK * ASTRIDE];
  __shared__ float Ws[GTK * HDIM];
  const int t = threadIdx.x;
  const int tr = t >> 4;
  const int tc = t & 15;
  const int rowbase = blockIdx.x * GTM;
  float acc[8][8];
  #pragma unroll
  for (int i = 0; i < 8; ++i)
    #pragma unroll
    for (int j = 0; j < 8; ++j) acc[i][j] = 0.f;

  for (int kc = 0; kc < HDIM; kc += GTK) {
    #pragma unroll
    for (int i = 0; i < 4; ++i) {
      int flat = i * 256 + t;
      int r = flat >> 3;
      int c4 = (flat & 7) << 2;
      int row = rowbase + r;
      float4 v = make_float4(0.f, 0.f, 0.f, 0.f);
      if (row < N)
        v = *reinterpret_cast<const float4*>(Ctot + (size_t)row * HDIM + kc + c4);
      As[(c4 + 0) * ASTRIDE + r] = v.x;
      As[(c4 + 1) * ASTRIDE + r] = v.y;
      As[(c4 + 2) * ASTRIDE + r] = v.z;
      As[(c4 + 3) * ASTRIDE + r] = v.w;
    }
    #pragma unroll
    for (int i = 0; i < 4; ++i) {
      int flat = i * 256 + t;
      int k = flat >> 5;
      int c4 = (flat & 31) << 2;
      *reinterpret_cast<float4*>(&Ws[k * HDIM + c4]) =
          *reinterpret_cast<const float4*>(W5 + (size_t)(kc + k) * HDIM + c4);
    }
    __syncthreads();
    #pragma unroll 4
    for (int k = 0; k < GTK; ++k) {
      float4 a0 = *reinterpret_cast<const float4*>(&As[k * ASTRIDE + tr * 8]);
      float4 a1 = *reinterpret_cast<const float4*>(&As[k * ASTRIDE + tr * 8 + 4]);
      float4 w0 = *reinterpret_cast<const float4*>(&Ws[k * HDIM + tc * 8]);
      float4 w1 = *reinterpret_cast<const float4*>(&Ws[k * HDIM + tc * 8 + 4]);
      float av[8] = {a0.x, a0.y, a0.z, a0.w, a1.x, a1.y, a1.z, a1.w};
      float wv[8] = {w0.x, w0.y, w0.z, w0.w, w1.x, w1.y, w1.z, w1.w};
      #pragma unroll
      for (int i = 0; i < 8; ++i)
        #pragma unroll
        for (int j = 0; j < 8; ++j) acc[i][j] += av[i] * wv[j];
    }
    __syncthreads();
  }

  const int col = tc * 8;
  #pragma unroll
  for (int rr = 0; rr < 8; ++rr) {
    int row = rowbase + tr * 8 + rr;
    if (row >= N) continue;
    size_t base = (size_t)row * HDIM + col;
    float4 hp0 = *reinterpret_cast<const float4*>(outi + base);
    float4 hp1 = *reinterpret_cast<const float4*>(outi + base + 4);
    float4 h0 = *reinterpret_cast<const float4*>(hi + base);
    float4 h1 = *reinterpret_cast<const float4*>(hi + base + 4);
    f16x8 zv = *reinterpret_cast<const f16x8*>(zb + base);
    float hpv[8] = {hp0.x, hp0.y, hp0.z, hp0.w, hp1.x, hp1.y, hp1.z, hp1.w};
    float hv[8]  = {h0.x, h0.y, h0.z, h0.w, h1.x, h1.y, h1.z, h1.w};
    float o[8];
    f16x8 ob;
    #pragma unroll
    for (int cc = 0; cc < 8; ++cc) {
      float v = acc[rr][cc] + b5[col + cc] + hpv[cc];
      float ht = tanhf(v);
      float z = 1.f / (1.f + expf(-(float)zv[cc]));
      o[cc] = z * hv[cc] + (1.f - z) * ht;
      ob[cc] = (f16)o[cc];
    }
    *reinterpret_cast<float4*>(outi + base)     = make_float4(o[0], o[1], o[2], o[3]);
    *reinterpret_cast<float4*>(outi + base + 4) = make_float4(o[4], o[5], o[6], o[7]);
    *reinterpret_cast<f16x8*>(xb + base) = ob;
  }
}

extern "C" void kernel_launch(void* const* d_in, const int* in_sizes, int n_in,
                              void* d_out, int out_size, void* d_ws, size_t ws_size,
                              hipStream_t stream) {
  const float* inp = (const float*)d_in[0];
  const int*   edg = (const int*)d_in[1];
  const float* h   = (const float*)d_in[2];
  const float* W   = (const float*)d_in[3];
  const float* b   = (const float*)d_in[4];
  float* out = (float*)d_out;

  const int NH = in_sizes[0];      // N*H
  const int N  = NH / HDIM;
  const int E  = in_sizes[1] / 2;
  const int L  = in_sizes[2] / NH;

  float* buf0 = (float*)d_ws;            // A / Ctot (fp32)
  float* buf1 = buf0 + (size_t)NH;       // Bh (fp32)
  f16* zb = (f16*)(buf1 + (size_t)NH);   // zpre f16
  f16* cb = zb + (size_t)NH;             // r*h f16
  f16* xb = cb + (size_t)NH;             // x f16
  f16* hb = xb + (size_t)NH;             // h_i f16
  int* deg     = (int*)(hb + (size_t)NH);
  int* offs    = deg + N;                // N+1 entries
  int* cursor  = offs + (N + 1);
  int* bsum    = cursor + N;             // 256
  int* boff    = bsum + 256;             // 256
  int* csr_src = boff + 256;             // E entries

  const int eblocks = (E + 255) / 256;
  const int nodeblocks = (N + 3) / 4;
  const int n4 = NH / 4;
  const int cvblocks = (n4 + 255) / 256;
  const int rowblocks = (N + GTM - 1) / GTM;
  const int chunk = (N + 255) / 256;     // <=256 requires N<=65536

  // ---- CSR build (once; reused by all aggregations) ----
  hipMemsetAsync(deg, 0, (size_t)N * sizeof(int), stream);
  hipLaunchKernelGGL(degcount_kernel, dim3(eblocks), dim3(256), 0, stream,
                     edg, deg, E);
  hipLaunchKernelGGL(scan_part_kernel, dim3(256), dim3(256), 0, stream,
                     deg, bsum, N, chunk);
  hipLaunchKernelGGL(scan_top_kernel, dim3(1), dim3(256), 0, stream,
                     bsum, boff, offs, N);
  hipLaunchKernelGGL(scan_fin_kernel, dim3(256), dim3(256), 0, stream,
                     deg, boff, offs, cursor, N, chunk);
  hipLaunchKernelGGL(fill_kernel, dim3(eblocks), dim3(256), 0, stream,
                     edg, cursor, csr_src, E);
  hipLaunchKernelGGL(convh_kernel, dim3(cvblocks), dim3(256), 0, stream,
                     inp, xb, n4);

  const float* x = inp;
  for (int i = 0; i < L; ++i) {
    const float* hi = h + (size_t)i * NH;
    const float* Wi = W + (size_t)i * 6 * HDIM * HDIM;
    const float* bi = b + (size_t)i * 6 * HDIM;
    float* outi = out + (size_t)i * NH;

    hipLaunchKernelGGL(convh_kernel, dim3(cvblocks), dim3(256), 0, stream,
                       hi, hb, n4);
    hipLaunchKernelGGL(pull2_kernel, dim3(nodeblocks), dim3(256), 0, stream,
                       csr_src, offs, x, hi, xb, hb, buf0, buf1, N);
    hipLaunchKernelGGL(gemm3_kernel, dim3(rowblocks, 3), dim3(256), 0, stream,
                       buf0, buf1, Wi, bi, hi, zb, cb, outi, N);
    hipLaunchKernelGGL(pull1_kernel, dim3(nodeblocks), dim3(256), 0, stream,
                       csr_src, offs, cb, buf0, N);
    // gemm_final also writes xb = f16(out) for the next layer's pull
    hipLaunchKernelGGL(gemm_final_kernel, dim3(rowblocks, 1), dim3(256), 0, stream,
                       buf0, Wi + (size_t)5 * HDIM * HDIM, bi + 5 * HDIM,
                       zb, hi, outi, xb, N);
    x = outi;
  }
}

// Round 5
// 893.319 us; speedup vs baseline: 18.5024x; 1.1434x over previous
//
#include <hip/hip_runtime.h>
#include <math.h>

#define HDIM 128

typedef _Float16 f16;
typedef __attribute__((ext_vector_type(2))) _Float16 f16x2;
typedef __attribute__((ext_vector_type(4))) _Float16 f16x4;
typedef __attribute__((ext_vector_type(8))) _Float16 f16x8;
typedef __attribute__((ext_vector_type(4))) float f32x4;

// ================= CSR build =================
__global__ __launch_bounds__(256) void degcount_kernel(
    const int* __restrict__ edg, int* __restrict__ deg, int E) {
  int e = blockIdx.x * 256 + threadIdx.x;
  if (e < E) atomicAdd(&deg[edg[E + e]], 1);
}

__global__ __launch_bounds__(256) void scan_part_kernel(
    const int* __restrict__ deg, int* __restrict__ bsum, int n, int chunk) {
  __shared__ int red[256];
  const int b = blockIdx.x, t = threadIdx.x;
  const int begin = b * chunk;
  const int end = min(begin + chunk, n);
  int s = 0;
  for (int i = begin + t; i < end; i += 256) s += deg[i];
  red[t] = s;
  __syncthreads();
  for (int off = 128; off > 0; off >>= 1) {
    if (t < off) red[t] += red[t + off];
    __syncthreads();
  }
  if (t == 0) bsum[b] = red[0];
}

__global__ __launch_bounds__(256) void scan_top_kernel(
    const int* __restrict__ bsum, int* __restrict__ boff,
    int* __restrict__ offs, int n) {
  __shared__ int sh[256];
  const int t = threadIdx.x;
  int v = bsum[t];
  sh[t] = v;
  __syncthreads();
  for (int off = 1; off < 256; off <<= 1) {
    int add = (t >= off) ? sh[t - off] : 0;
    __syncthreads();
    sh[t] += add;
    __syncthreads();
  }
  boff[t] = sh[t] - v;
  if (t == 255) offs[n] = sh[255];
}

__global__ __launch_bounds__(256) void scan_fin_kernel(
    const int* __restrict__ deg, const int* __restrict__ boff,
    int* __restrict__ offs, int* __restrict__ cursor, int n, int chunk) {
  __shared__ int sh[256];
  const int b = blockIdx.x, t = threadIdx.x;
  const int idx = b * chunk + t;
  int v = (t < chunk && idx < n) ? deg[idx] : 0;
  sh[t] = v;
  __syncthreads();
  for (int off = 1; off < 256; off <<= 1) {
    int add = (t >= off) ? sh[t - off] : 0;
    __syncthreads();
    sh[t] += add;
    __syncthreads();
  }
  if (t < chunk && idx < n) {
    int o = boff[b] + sh[t] - v;
    offs[idx] = o;
    cursor[idx] = o;
  }
}

// 4 edges per thread: amortize atomic-return latency across 4 chains
__global__ __launch_bounds__(256) void fill_kernel(
    const int* __restrict__ edg, int* __restrict__ cursor,
    int* __restrict__ csr_src, int E) {
  int i = blockIdx.x * 256 + threadIdx.x;
  int e0 = i * 4;
  if (e0 >= E) return;
  if (e0 + 4 <= E && (E & 3) == 0) {
    int4 s4 = *reinterpret_cast<const int4*>(edg + e0);
    int4 d4 = *reinterpret_cast<const int4*>(edg + E + e0);
    int p0 = atomicAdd(&cursor[d4.x], 1);
    int p1 = atomicAdd(&cursor[d4.y], 1);
    int p2 = atomicAdd(&cursor[d4.z], 1);
    int p3 = atomicAdd(&cursor[d4.w], 1);
    csr_src[p0] = s4.x;
    csr_src[p1] = s4.y;
    csr_src[p2] = s4.z;
    csr_src[p3] = s4.w;
  } else {
    for (int e = e0; e < min(e0 + 4, E); ++e) {
      int pos = atomicAdd(&cursor[edg[E + e]], 1);
      csr_src[pos] = edg[e];
    }
  }
}

// ================= fp32 -> fp16 conversion =================
__global__ __launch_bounds__(256) void convh_kernel(
    const float* __restrict__ s, f16* __restrict__ d, int n4) {
  int i = blockIdx.x * 256 + threadIdx.x;
  if (i < n4) {
    float4 v = reinterpret_cast<const float4*>(s)[i];
    f16x4 o;
    o[0] = (f16)v.x; o[1] = (f16)v.y; o[2] = (f16)v.z; o[3] = (f16)v.w;
    reinterpret_cast<f16x4*>(d)[i] = o;
  }
}

// ================= W transpose + fp16: WT[gate][n][k] =================
// grid: (16 tiles, L*6 gates); 32x32 tile transpose via LDS
__global__ __launch_bounds__(256) void transw_kernel(
    const float* __restrict__ W, f16* __restrict__ WT) {
  __shared__ float sh[32][33];
  const int g = blockIdx.y;
  const int ti = blockIdx.x >> 2;   // row-tile of W (k dim)
  const int tj = blockIdx.x & 3;    // col-tile of W (n dim)
  const float* __restrict__ wp = W + (size_t)g * HDIM * HDIM;
  f16* __restrict__ op = WT + (size_t)g * HDIM * HDIM;
  const int t = threadIdx.x;
  #pragma unroll
  for (int it = 0; it < 4; ++it) {
    int elem = it * 256 + t;
    int r = elem >> 5, c = elem & 31;
    sh[r][c] = wp[(size_t)(ti * 32 + r) * HDIM + tj * 32 + c];
  }
  __syncthreads();
  #pragma unroll
  for (int it = 0; it < 4; ++it) {
    int elem = it * 256 + t;
    int cc = elem >> 5, rr = elem & 31;
    op[(size_t)(tj * 32 + cc) * HDIM + ti * 32 + rr] = (f16)sh[rr][cc];
  }
}

// ================= pull aggregation (fp16 gather+store, fp32 accum) =====
__global__ __launch_bounds__(256) void pull2_kernel(
    const int* __restrict__ csr_src, const int* __restrict__ offs,
    const float* __restrict__ xf, const float* __restrict__ hf,
    const f16* __restrict__ xb, const f16* __restrict__ hb,
    f16* __restrict__ A, f16* __restrict__ Bh, int N) {
  const int node = blockIdx.x * 4 + (threadIdx.x >> 6);
  if (node >= N) return;
  const int lane = threadIdx.x & 63;
  const int half = lane >> 5;
  const int c = (lane & 31) << 2;
  const float* __restrict__ selfp = half ? hf : xf;
  const f16* __restrict__ nb = half ? hb : xb;
  f16* __restrict__ dst = half ? Bh : A;
  const int s = offs[node];
  const int e = offs[node + 1];
  float4 acc = *reinterpret_cast<const float4*>(selfp + (size_t)node * HDIM + c);
  int k = s;
  for (; k + 4 <= e; k += 4) {
    int j0 = csr_src[k];
    int j1 = csr_src[k + 1];
    int j2 = csr_src[k + 2];
    int j3 = csr_src[k + 3];
    f16x4 u0 = *reinterpret_cast<const f16x4*>(nb + (size_t)j0 * HDIM + c);
    f16x4 u1 = *reinterpret_cast<const f16x4*>(nb + (size_t)j1 * HDIM + c);
    f16x4 u2 = *reinterpret_cast<const f16x4*>(nb + (size_t)j2 * HDIM + c);
    f16x4 u3 = *reinterpret_cast<const f16x4*>(nb + (size_t)j3 * HDIM + c);
    acc.x += (float)u0[0] + (float)u1[0] + (float)u2[0] + (float)u3[0];
    acc.y += (float)u0[1] + (float)u1[1] + (float)u2[1] + (float)u3[1];
    acc.z += (float)u0[2] + (float)u1[2] + (float)u2[2] + (float)u3[2];
    acc.w += (float)u0[3] + (float)u1[3] + (float)u2[3] + (float)u3[3];
  }
  for (; k < e; ++k) {
    f16x4 u0 = *reinterpret_cast<const f16x4*>(nb + (size_t)csr_src[k] * HDIM + c);
    acc.x += (float)u0[0];
    acc.y += (float)u0[1];
    acc.z += (float)u0[2];
    acc.w += (float)u0[3];
  }
  f16x4 o;
  o[0] = (f16)acc.x; o[1] = (f16)acc.y; o[2] = (f16)acc.z; o[3] = (f16)acc.w;
  *reinterpret_cast<f16x4*>(dst + (size_t)node * HDIM + c) = o;
}

__global__ __launch_bounds__(256) void pull1_kernel(
    const int* __restrict__ csr_src, const int* __restrict__ offs,
    const f16* __restrict__ cb, f16* __restrict__ Ctot, int N) {
  const int node = blockIdx.x * 4 + (threadIdx.x >> 6);
  if (node >= N) return;
  const int lane = threadIdx.x & 63;
  const int c = lane << 1;
  const int s = offs[node];
  const int e = offs[node + 1];
  f16x2 us = *reinterpret_cast<const f16x2*>(cb + (size_t)node * HDIM + c);
  float2 acc = make_float2((float)us[0], (float)us[1]);
  int k = s;
  for (; k + 4 <= e; k += 4) {
    int j0 = csr_src[k];
    int j1 = csr_src[k + 1];
    int j2 = csr_src[k + 2];
    int j3 = csr_src[k + 3];
    f16x2 u0 = *reinterpret_cast<const f16x2*>(cb + (size_t)j0 * HDIM + c);
    f16x2 u1 = *reinterpret_cast<const f16x2*>(cb + (size_t)j1 * HDIM + c);
    f16x2 u2 = *reinterpret_cast<const f16x2*>(cb + (size_t)j2 * HDIM + c);
    f16x2 u3 = *reinterpret_cast<const f16x2*>(cb + (size_t)j3 * HDIM + c);
    acc.x += (float)u0[0] + (float)u1[0] + (float)u2[0] + (float)u3[0];
    acc.y += (float)u0[1] + (float)u1[1] + (float)u2[1] + (float)u3[1];
  }
  for (; k < e; ++k) {
    f16x2 u0 = *reinterpret_cast<const f16x2*>(cb + (size_t)csr_src[k] * HDIM + c);
    acc.x += (float)u0[0];
    acc.y += (float)u0[1];
  }
  f16x2 o;
  o[0] = (f16)acc.x; o[1] = (f16)acc.y;
  *reinterpret_cast<f16x2*>(Ctot + (size_t)node * HDIM + c) = o;
}

// ================= MFMA gate GEMM =================
// 64 rows/block, 4 waves in 2x2; wave = 32 rows x 64 cols; K=128 in LDS.
// mfma_f32_16x16x32_f16: A[m=lane&15][k=quad*8+j]; B[k][n=lane&15];
// C/D: col=lane&15, row=quad*4+reg.
// group 0 -> zb f16 ; 1 -> cb = f16(sigmoid(.)*hi) ; 2 -> hpre fp32 (outi)
__global__ __launch_bounds__(256, 3) void gemm3_kernel(
    const f16* __restrict__ A, const f16* __restrict__ Bh,
    const f16* __restrict__ WT, const float* __restrict__ b,
    const float* __restrict__ hi, f16* __restrict__ zb,
    f16* __restrict__ cb, float* __restrict__ hpre, int N) {
  __shared__ f16 As[64 * 136];
  __shared__ f16 Ws[128 * 136];
  const int t = threadIdx.x;
  const int w = t >> 6, wr = w >> 1, wc = w & 1;
  const int lane = t & 63, ln15 = lane & 15, quad = lane >> 4;
  const int row0 = blockIdx.x * 64;
  const int group = blockIdx.y;
  f32x4 acc[2][4];
  #pragma unroll
  for (int i = 0; i < 2; ++i)
    #pragma unroll
    for (int j = 0; j < 4; ++j) acc[i][j] = (f32x4){0.f, 0.f, 0.f, 0.f};

  const int nphase = (group < 2) ? 2 : 1;
  for (int phase = 0; phase < nphase; ++phase) {
    const f16* __restrict__ src = phase ? Bh : A;
    const f16* __restrict__ wp = WT + (size_t)(group * 2 + phase) * HDIM * HDIM;
    #pragma unroll
    for (int i = 0; i < 4; ++i) {  // A tile: 64x128
      int flat = i * 256 + t;
      int r = flat >> 4;
      int o = (flat & 15) * 8;
      int row = row0 + r;
      f16x8 v{};
      if (row < N) v = *reinterpret_cast<const f16x8*>(src + (size_t)row * HDIM + o);
      *reinterpret_cast<f16x8*>(&As[r * 136 + o]) = v;
    }
    #pragma unroll
    for (int i = 0; i < 8; ++i) {  // W tile: 128(n) x 128(k)
      int flat = i * 256 + t;
      int n = flat >> 4;
      int o = (flat & 15) * 8;
      *reinterpret_cast<f16x8*>(&Ws[n * 136 + o]) =
          *reinterpret_cast<const f16x8*>(wp + (size_t)n * HDIM + o);
    }
    __syncthreads();
    #pragma unroll
    for (int s = 0; s < 4; ++s) {
      f16x8 a0 = *reinterpret_cast<const f16x8*>(
          &As[(wr * 32 + ln15) * 136 + s * 32 + quad * 8]);
      f16x8 a1 = *reinterpret_cast<const f16x8*>(
          &As[(wr * 32 + 16 + ln15) * 136 + s * 32 + quad * 8]);
      #pragma unroll
      for (int ni = 0; ni < 4; ++ni) {
        f16x8 bf = *reinterpret_cast<const f16x8*>(
            &Ws[(wc * 64 + ni * 16 + ln15) * 136 + s * 32 + quad * 8]);
        acc[0][ni] = __builtin_amdgcn_mfma_f32_16x16x32_f16(a0, bf, acc[0][ni], 0, 0, 0);
        acc[1][ni] = __builtin_amdgcn_mfma_f32_16x16x32_f16(a1, bf, acc[1][ni], 0, 0, 0);
      }
    }
    __syncthreads();
  }

  // epilogue
  #pragma unroll
  for (int ni = 0; ni < 4; ++ni) {
    const int col = wc * 64 + ni * 16 + ln15;
    float bias = b[(group * 2) * HDIM + col];
    if (group < 2) bias += b[(group * 2 + 1) * HDIM + col];
    #pragma unroll
    for (int mi = 0; mi < 2; ++mi) {
      #pragma unroll
      for (int r = 0; r < 4; ++r) {
        int row = row0 + wr * 32 + mi * 16 + quad * 4 + r;
        if (row >= N) continue;
        size_t idx = (size_t)row * HDIM + col;
        float v = acc[mi][ni][r] + bias;
        if (group == 0) {
          zb[idx] = (f16)v;
        } else if (group == 1) {
          float rg = 1.f / (1.f + expf(-v));
          cb[idx] = (f16)(rg * hi[idx]);
        } else {
          hpre[idx] = v;
        }
      }
    }
  }
}

// ================= MFMA final GEMM + GRU combine =================
__global__ __launch_bounds__(256, 3) void gemm_final_kernel(
    const f16* __restrict__ Ctot, const f16* __restrict__ WT5,
    const float* __restrict__ b5, const f16* __restrict__ zb,
    const float* __restrict__ hi, float* __restrict__ outi,
    f16* __restrict__ xb, int N) {
  __shared__ f16 As[64 * 136];
  __shared__ f16 Ws[128 * 136];
  const int t = threadIdx.x;
  const int w = t >> 6, wr = w >> 1, wc = w & 1;
  const int lane = t & 63, ln15 = lane & 15, quad = lane >> 4;
  const int row0 = blockIdx.x * 64;
  f32x4 acc[2][4];
  #pragma unroll
  for (int i = 0; i < 2; ++i)
    #pragma unroll
    for (int j = 0; j < 4; ++j) acc[i][j] = (f32x4){0.f, 0.f, 0.f, 0.f};

  #pragma unroll
  for (int i = 0; i < 4; ++i) {
    int flat = i * 256 + t;
    int r = flat >> 4;
    int o = (flat & 15) * 8;
    int row = row0 + r;
    f16x8 v{};
    if (row < N) v = *reinterpret_cast<const f16x8*>(Ctot + (size_t)row * HDIM + o);
    *reinterpret_cast<f16x8*>(&As[r * 136 + o]) = v;
  }
  #pragma unroll
  for (int i = 0; i < 8; ++i) {
    int flat = i * 256 + t;
    int n = flat >> 4;
    int o = (flat & 15) * 8;
    *reinterpret_cast<f16x8*>(&Ws[n * 136 + o]) =
        *reinterpret_cast<const f16x8*>(WT5 + (size_t)n * HDIM + o);
  }
  __syncthreads();
  #pragma unroll
  for (int s = 0; s < 4; ++s) {
    f16x8 a0 = *reinterpret_cast<const f16x8*>(
        &As[(wr * 32 + ln15) * 136 + s * 32 + quad * 8]);
    f16x8 a1 = *reinterpret_cast<const f16x8*>(
        &As[(wr * 32 + 16 + ln15) * 136 + s * 32 + quad * 8]);
    #pragma unroll
    for (int ni = 0; ni < 4; ++ni) {
      f16x8 bf = *reinterpret_cast<const f16x8*>(
          &Ws[(wc * 64 + ni * 16 + ln15) * 136 + s * 32 + quad * 8]);
      acc[0][ni] = __builtin_amdgcn_mfma_f32_16x16x32_f16(a0, bf, acc[0][ni], 0, 0, 0);
      acc[1][ni] = __builtin_amdgcn_mfma_f32_16x16x32_f16(a1, bf, acc[1][ni], 0, 0, 0);
    }
  }

  #pragma unroll
  for (int ni = 0; ni < 4; ++ni) {
    const int col = wc * 64 + ni * 16 + ln15;
    float bias = b5[col];
    #pragma unroll
    for (int mi = 0; mi < 2; ++mi) {
      #pragma unroll
      for (int r = 0; r < 4; ++r) {
        int row = row0 + wr * 32 + mi * 16 + quad * 4 + r;
        if (row >= N) continue;
        size_t idx = (size_t)row * HDIM + col;
        float v = acc[mi][ni][r] + bias + outi[idx];  // + hpre
        float ht = tanhf(v);
        float z = 1.f / (1.f + expf(-(float)zb[idx]));
        float o = z * hi[idx] + (1.f - z) * ht;
        outi[idx] = o;
        xb[idx] = (f16)o;
      }
    }
  }
}

extern "C" void kernel_launch(void* const* d_in, const int* in_sizes, int n_in,
                              void* d_out, int out_size, void* d_ws, size_t ws_size,
                              hipStream_t stream) {
  const float* inp = (const float*)d_in[0];
  const int*   edg = (const int*)d_in[1];
  const float* h   = (const float*)d_in[2];
  const float* W   = (const float*)d_in[3];
  const float* b   = (const float*)d_in[4];
  float* out = (float*)d_out;

  const int NH = in_sizes[0];      // N*H
  const int N  = NH / HDIM;
  const int E  = in_sizes[1] / 2;
  const int L  = in_sizes[2] / NH;

  f16* Af   = (f16*)d_ws;               // A aggregate / Ctot (reused)
  f16* Bhf  = Af + (size_t)NH;          // Bh aggregate
  f16* zbuf = Bhf + (size_t)NH;         // zpre
  f16* cbuf = zbuf + (size_t)NH;        // r*h
  f16* xbuf = cbuf + (size_t)NH;        // x f16
  f16* hbuf = xbuf + (size_t)NH;        // h_i f16
  f16* WT   = hbuf + (size_t)NH;        // L*6*H*H transposed f16 weights
  int* deg     = (int*)(WT + (size_t)L * 6 * HDIM * HDIM);
  int* offs    = deg + N;               // N+1
  int* cursor  = offs + (N + 1);
  int* bsum    = cursor + N;            // 256
  int* boff    = bsum + 256;            // 256
  int* csr_src = boff + 256;            // E

  const int eblocks = (E + 255) / 256;
  const int fblocks = (E + 1023) / 1024;
  const int nodeblocks = (N + 3) / 4;
  const int n4 = NH / 4;
  const int cvblocks = (n4 + 255) / 256;
  const int rowblocks = (N + 63) / 64;
  const int chunk = (N + 255) / 256;    // <=256 requires N<=65536

  // ---- one-time per call: CSR build, weight transpose, input f16 ----
  hipMemsetAsync(deg, 0, (size_t)N * sizeof(int), stream);
  hipLaunchKernelGGL(degcount_kernel, dim3(eblocks), dim3(256), 0, stream,
                     edg, deg, E);
  hipLaunchKernelGGL(scan_part_kernel, dim3(256), dim3(256), 0, stream,
                     deg, bsum, N, chunk);
  hipLaunchKernelGGL(scan_top_kernel, dim3(1), dim3(256), 0, stream,
                     bsum, boff, offs, N);
  hipLaunchKernelGGL(scan_fin_kernel, dim3(256), dim3(256), 0, stream,
                     deg, boff, offs, cursor, N, chunk);
  hipLaunchKernelGGL(fill_kernel, dim3(fblocks), dim3(256), 0, stream,
                     edg, cursor, csr_src, E);
  hipLaunchKernelGGL(transw_kernel, dim3(16, L * 6), dim3(256), 0, stream,
                     W, WT);
  hipLaunchKernelGGL(convh_kernel, dim3(cvblocks), dim3(256), 0, stream,
                     inp, xbuf, n4);

  const float* x = inp;
  for (int i = 0; i < L; ++i) {
    const float* hi = h + (size_t)i * NH;
    const f16* WTi = WT + (size_t)i * 6 * HDIM * HDIM;
    const float* bi = b + (size_t)i * 6 * HDIM;
    float* outi = out + (size_t)i * NH;

    hipLaunchKernelGGL(convh_kernel, dim3(cvblocks), dim3(256), 0, stream,
                       hi, hbuf, n4);
    hipLaunchKernelGGL(pull2_kernel, dim3(nodeblocks), dim3(256), 0, stream,
                       csr_src, offs, x, hi, xbuf, hbuf, Af, Bhf, N);
    hipLaunchKernelGGL(gemm3_kernel, dim3(rowblocks, 3), dim3(256), 0, stream,
                       Af, Bhf, WTi, bi, hi, zbuf, cbuf, outi, N);
    hipLaunchKernelGGL(pull1_kernel, dim3(nodeblocks), dim3(256), 0, stream,
                       csr_src, offs, cbuf, Af, N);   // Af reused as Ctot
    hipLaunchKernelGGL(gemm_final_kernel, dim3(rowblocks), dim3(256), 0, stream,
                       Af, WTi + (size_t)5 * HDIM * HDIM, bi + 5 * HDIM,
                       zbuf, hi, outi, xbuf, N);
    x = outi;
  }
}

// Round 6
// 787.115 us; speedup vs baseline: 20.9989x; 1.1349x over previous
//
#include <hip/hip_runtime.h>
#include <math.h>

#define HDIM 128

typedef _Float16 f16;
typedef unsigned short u16;
typedef __attribute__((ext_vector_type(2))) _Float16 f16x2;
typedef __attribute__((ext_vector_type(4))) _Float16 f16x4;
typedef __attribute__((ext_vector_type(8))) _Float16 f16x8;
typedef __attribute__((ext_vector_type(4))) float f32x4;

// ================= CSR build =================
// counts in-degree AND records each edge's rank within its dst bucket
__global__ __launch_bounds__(256) void degrank_kernel(
    const int* __restrict__ edg, int* __restrict__ deg,
    u16* __restrict__ rank, int E) {
  int e = blockIdx.x * 256 + threadIdx.x;
  if (e < E) rank[e] = (u16)atomicAdd(&deg[edg[E + e]], 1);
}

__global__ __launch_bounds__(256) void scan_part_kernel(
    const int* __restrict__ deg, int* __restrict__ bsum, int n, int chunk) {
  __shared__ int red[256];
  const int b = blockIdx.x, t = threadIdx.x;
  const int begin = b * chunk;
  const int end = min(begin + chunk, n);
  int s = 0;
  for (int i = begin + t; i < end; i += 256) s += deg[i];
  red[t] = s;
  __syncthreads();
  for (int off = 128; off > 0; off >>= 1) {
    if (t < off) red[t] += red[t + off];
    __syncthreads();
  }
  if (t == 0) bsum[b] = red[0];
}

__global__ __launch_bounds__(256) void scan_top_kernel(
    const int* __restrict__ bsum, int* __restrict__ boff,
    int* __restrict__ offs, int n) {
  __shared__ int sh[256];
  const int t = threadIdx.x;
  int v = bsum[t];
  sh[t] = v;
  __syncthreads();
  for (int off = 1; off < 256; off <<= 1) {
    int add = (t >= off) ? sh[t - off] : 0;
    __syncthreads();
    sh[t] += add;
    __syncthreads();
  }
  boff[t] = sh[t] - v;
  if (t == 255) offs[n] = sh[255];
}

__global__ __launch_bounds__(256) void scan_fin_kernel(
    const int* __restrict__ deg, const int* __restrict__ boff,
    int* __restrict__ offs, int n, int chunk) {
  __shared__ int sh[256];
  const int b = blockIdx.x, t = threadIdx.x;
  const int idx = b * chunk + t;
  int v = (t < chunk && idx < n) ? deg[idx] : 0;
  sh[t] = v;
  __syncthreads();
  for (int off = 1; off < 256; off <<= 1) {
    int add = (t >= off) ? sh[t - off] : 0;
    __syncthreads();
    sh[t] += add;
    __syncthreads();
  }
  if (t < chunk && idx < n) offs[idx] = boff[b] + sh[t] - v;
}

// atomic-free fill: pos = offs[dst] + rank[e]; u16 scattered store
__global__ __launch_bounds__(256) void fill_kernel(
    const int* __restrict__ edg, const int* __restrict__ offs,
    const u16* __restrict__ rank, u16* __restrict__ csr_src, int E) {
  int i = blockIdx.x * 256 + threadIdx.x;
  int e0 = i * 4;
  if (e0 >= E) return;
  if (e0 + 4 <= E) {
    int4 s4 = *reinterpret_cast<const int4*>(edg + e0);
    int4 d4 = *reinterpret_cast<const int4*>(edg + E + e0);
    ushort4 r4 = *reinterpret_cast<const ushort4*>(rank + e0);
    csr_src[offs[d4.x] + r4.x] = (u16)s4.x;
    csr_src[offs[d4.y] + r4.y] = (u16)s4.y;
    csr_src[offs[d4.z] + r4.z] = (u16)s4.z;
    csr_src[offs[d4.w] + r4.w] = (u16)s4.w;
  } else {
    for (int e = e0; e < E; ++e)
      csr_src[offs[edg[E + e]] + rank[e]] = (u16)edg[e];
  }
}

// ================= fp32 -> fp16 conversion =================
__global__ __launch_bounds__(256) void convh_kernel(
    const float* __restrict__ s, f16* __restrict__ d, int n4) {
  int i = blockIdx.x * 256 + threadIdx.x;
  if (i < n4) {
    float4 v = reinterpret_cast<const float4*>(s)[i];
    f16x4 o;
    o[0] = (f16)v.x; o[1] = (f16)v.y; o[2] = (f16)v.z; o[3] = (f16)v.w;
    reinterpret_cast<f16x4*>(d)[i] = o;
  }
}

// ================= W transpose + fp16: WT[gate][n][k] =================
__global__ __launch_bounds__(256) void transw_kernel(
    const float* __restrict__ W, f16* __restrict__ WT) {
  __shared__ float sh[32][33];
  const int g = blockIdx.y;
  const int ti = blockIdx.x >> 2;
  const int tj = blockIdx.x & 3;
  const float* __restrict__ wp = W + (size_t)g * HDIM * HDIM;
  f16* __restrict__ op = WT + (size_t)g * HDIM * HDIM;
  const int t = threadIdx.x;
  #pragma unroll
  for (int it = 0; it < 4; ++it) {
    int elem = it * 256 + t;
    int r = elem >> 5, c = elem & 31;
    sh[r][c] = wp[(size_t)(ti * 32 + r) * HDIM + tj * 32 + c];
  }
  __syncthreads();
  #pragma unroll
  for (int it = 0; it < 4; ++it) {
    int elem = it * 256 + t;
    int cc = elem >> 5, rr = elem & 31;
    op[(size_t)(tj * 32 + cc) * HDIM + ti * 32 + rr] = (f16)sh[rr][cc];
  }
}

// ================= pull aggregation (fp16 gather+store, fp32 accum) =====
__global__ __launch_bounds__(256) void pull2_kernel(
    const u16* __restrict__ csr_src, const int* __restrict__ offs,
    const float* __restrict__ xf, const float* __restrict__ hf,
    const f16* __restrict__ xb, const f16* __restrict__ hb,
    f16* __restrict__ A, f16* __restrict__ Bh, int N) {
  const int node = blockIdx.x * 4 + (threadIdx.x >> 6);
  if (node >= N) return;
  const int lane = threadIdx.x & 63;
  const int half = lane >> 5;
  const int c = (lane & 31) << 2;
  const float* __restrict__ selfp = half ? hf : xf;
  const f16* __restrict__ nb = half ? hb : xb;
  f16* __restrict__ dst = half ? Bh : A;
  const int s = offs[node];
  const int e = offs[node + 1];
  float4 acc = *reinterpret_cast<const float4*>(selfp + (size_t)node * HDIM + c);
  int k = s;
  for (; k + 4 <= e; k += 4) {
    int j0 = csr_src[k];
    int j1 = csr_src[k + 1];
    int j2 = csr_src[k + 2];
    int j3 = csr_src[k + 3];
    f16x4 u0 = *reinterpret_cast<const f16x4*>(nb + (size_t)j0 * HDIM + c);
    f16x4 u1 = *reinterpret_cast<const f16x4*>(nb + (size_t)j1 * HDIM + c);
    f16x4 u2 = *reinterpret_cast<const f16x4*>(nb + (size_t)j2 * HDIM + c);
    f16x4 u3 = *reinterpret_cast<const f16x4*>(nb + (size_t)j3 * HDIM + c);
    acc.x += (float)u0[0] + (float)u1[0] + (float)u2[0] + (float)u3[0];
    acc.y += (float)u0[1] + (float)u1[1] + (float)u2[1] + (float)u3[1];
    acc.z += (float)u0[2] + (float)u1[2] + (float)u2[2] + (float)u3[2];
    acc.w += (float)u0[3] + (float)u1[3] + (float)u2[3] + (float)u3[3];
  }
  for (; k < e; ++k) {
    f16x4 u0 = *reinterpret_cast<const f16x4*>(nb + (size_t)csr_src[k] * HDIM + c);
    acc.x += (float)u0[0];
    acc.y += (float)u0[1];
    acc.z += (float)u0[2];
    acc.w += (float)u0[3];
  }
  f16x4 o;
  o[0] = (f16)acc.x; o[1] = (f16)acc.y; o[2] = (f16)acc.z; o[3] = (f16)acc.w;
  *reinterpret_cast<f16x4*>(dst + (size_t)node * HDIM + c) = o;
}

__global__ __launch_bounds__(256) void pull1_kernel(
    const u16* __restrict__ csr_src, const int* __restrict__ offs,
    const f16* __restrict__ cb, f16* __restrict__ Ctot, int N) {
  const int node = blockIdx.x * 4 + (threadIdx.x >> 6);
  if (node >= N) return;
  const int lane = threadIdx.x & 63;
  const int c = lane << 1;
  const int s = offs[node];
  const int e = offs[node + 1];
  f16x2 us = *reinterpret_cast<const f16x2*>(cb + (size_t)node * HDIM + c);
  float2 acc = make_float2((float)us[0], (float)us[1]);
  int k = s;
  for (; k + 4 <= e; k += 4) {
    int j0 = csr_src[k];
    int j1 = csr_src[k + 1];
    int j2 = csr_src[k + 2];
    int j3 = csr_src[k + 3];
    f16x2 u0 = *reinterpret_cast<const f16x2*>(cb + (size_t)j0 * HDIM + c);
    f16x2 u1 = *reinterpret_cast<const f16x2*>(cb + (size_t)j1 * HDIM + c);
    f16x2 u2 = *reinterpret_cast<const f16x2*>(cb + (size_t)j2 * HDIM + c);
    f16x2 u3 = *reinterpret_cast<const f16x2*>(cb + (size_t)j3 * HDIM + c);
    acc.x += (float)u0[0] + (float)u1[0] + (float)u2[0] + (float)u3[0];
    acc.y += (float)u0[1] + (float)u1[1] + (float)u2[1] + (float)u3[1];
  }
  for (; k < e; ++k) {
    f16x2 u0 = *reinterpret_cast<const f16x2*>(cb + (size_t)csr_src[k] * HDIM + c);
    acc.x += (float)u0[0];
    acc.y += (float)u0[1];
  }
  f16x2 o;
  o[0] = (f16)acc.x; o[1] = (f16)acc.y;
  *reinterpret_cast<f16x2*>(Ctot + (size_t)node * HDIM + c) = o;
}

// ================= MFMA gate GEMM =================
__global__ __launch_bounds__(256, 3) void gemm3_kernel(
    const f16* __restrict__ A, const f16* __restrict__ Bh,
    const f16* __restrict__ WT, const float* __restrict__ b,
    const float* __restrict__ hi, f16* __restrict__ zb,
    f16* __restrict__ cb, float* __restrict__ hpre, int N) {
  __shared__ f16 As[64 * 136];
  __shared__ f16 Ws[128 * 136];
  const int t = threadIdx.x;
  const int w = t >> 6, wr = w >> 1, wc = w & 1;
  const int lane = t & 63, ln15 = lane & 15, quad = lane >> 4;
  const int row0 = blockIdx.x * 64;
  const int group = blockIdx.y;
  f32x4 acc[2][4];
  #pragma unroll
  for (int i = 0; i < 2; ++i)
    #pragma unroll
    for (int j = 0; j < 4; ++j) acc[i][j] = (f32x4){0.f, 0.f, 0.f, 0.f};

  const int nphase = (group < 2) ? 2 : 1;
  for (int phase = 0; phase < nphase; ++phase) {
    const f16* __restrict__ src = phase ? Bh : A;
    const f16* __restrict__ wp = WT + (size_t)(group * 2 + phase) * HDIM * HDIM;
    #pragma unroll
    for (int i = 0; i < 4; ++i) {
      int flat = i * 256 + t;
      int r = flat >> 4;
      int o = (flat & 15) * 8;
      int row = row0 + r;
      f16x8 v{};
      if (row < N) v = *reinterpret_cast<const f16x8*>(src + (size_t)row * HDIM + o);
      *reinterpret_cast<f16x8*>(&As[r * 136 + o]) = v;
    }
    #pragma unroll
    for (int i = 0; i < 8; ++i) {
      int flat = i * 256 + t;
      int n = flat >> 4;
      int o = (flat & 15) * 8;
      *reinterpret_cast<f16x8*>(&Ws[n * 136 + o]) =
          *reinterpret_cast<const f16x8*>(wp + (size_t)n * HDIM + o);
    }
    __syncthreads();
    #pragma unroll
    for (int s = 0; s < 4; ++s) {
      f16x8 a0 = *reinterpret_cast<const f16x8*>(
          &As[(wr * 32 + ln15) * 136 + s * 32 + quad * 8]);
      f16x8 a1 = *reinterpret_cast<const f16x8*>(
          &As[(wr * 32 + 16 + ln15) * 136 + s * 32 + quad * 8]);
      #pragma unroll
      for (int ni = 0; ni < 4; ++ni) {
        f16x8 bf = *reinterpret_cast<const f16x8*>(
            &Ws[(wc * 64 + ni * 16 + ln15) * 136 + s * 32 + quad * 8]);
        acc[0][ni] = __builtin_amdgcn_mfma_f32_16x16x32_f16(a0, bf, acc[0][ni], 0, 0, 0);
        acc[1][ni] = __builtin_amdgcn_mfma_f32_16x16x32_f16(a1, bf, acc[1][ni], 0, 0, 0);
      }
    }
    __syncthreads();
  }

  #pragma unroll
  for (int ni = 0; ni < 4; ++ni) {
    const int col = wc * 64 + ni * 16 + ln15;
    float bias = b[(group * 2) * HDIM + col];
    if (group < 2) bias += b[(group * 2 + 1) * HDIM + col];
    #pragma unroll
    for (int mi = 0; mi < 2; ++mi) {
      #pragma unroll
      for (int r = 0; r < 4; ++r) {
        int row = row0 + wr * 32 + mi * 16 + quad * 4 + r;
        if (row >= N) continue;
        size_t idx = (size_t)row * HDIM + col;
        float v = acc[mi][ni][r] + bias;
        if (group == 0) {
          zb[idx] = (f16)v;
        } else if (group == 1) {
          float rg = 1.f / (1.f + expf(-v));
          cb[idx] = (f16)(rg * hi[idx]);
        } else {
          hpre[idx] = v;
        }
      }
    }
  }
}

// ================= MFMA final GEMM + GRU combine =================
__global__ __launch_bounds__(256, 3) void gemm_final_kernel(
    const f16* __restrict__ Ctot, const f16* __restrict__ WT5,
    const float* __restrict__ b5, const f16* __restrict__ zb,
    const float* __restrict__ hi, float* __restrict__ outi,
    f16* __restrict__ xb, int N) {
  __shared__ f16 As[64 * 136];
  __shared__ f16 Ws[128 * 136];
  const int t = threadIdx.x;
  const int w = t >> 6, wr = w >> 1, wc = w & 1;
  const int lane = t & 63, ln15 = lane & 15, quad = lane >> 4;
  const int row0 = blockIdx.x * 64;
  f32x4 acc[2][4];
  #pragma unroll
  for (int i = 0; i < 2; ++i)
    #pragma unroll
    for (int j = 0; j < 4; ++j) acc[i][j] = (f32x4){0.f, 0.f, 0.f, 0.f};

  #pragma unroll
  for (int i = 0; i < 4; ++i) {
    int flat = i * 256 + t;
    int r = flat >> 4;
    int o = (flat & 15) * 8;
    int row = row0 + r;
    f16x8 v{};
    if (row < N) v = *reinterpret_cast<const f16x8*>(Ctot + (size_t)row * HDIM + o);
    *reinterpret_cast<f16x8*>(&As[r * 136 + o]) = v;
  }
  #pragma unroll
  for (int i = 0; i < 8; ++i) {
    int flat = i * 256 + t;
    int n = flat >> 4;
    int o = (flat & 15) * 8;
    *reinterpret_cast<f16x8*>(&Ws[n * 136 + o]) =
        *reinterpret_cast<const f16x8*>(WT5 + (size_t)n * HDIM + o);
  }
  __syncthreads();
  #pragma unroll
  for (int s = 0; s < 4; ++s) {
    f16x8 a0 = *reinterpret_cast<const f16x8*>(
        &As[(wr * 32 + ln15) * 136 + s * 32 + quad * 8]);
    f16x8 a1 = *reinterpret_cast<const f16x8*>(
        &As[(wr * 32 + 16 + ln15) * 136 + s * 32 + quad * 8]);
    #pragma unroll
    for (int ni = 0; ni < 4; ++ni) {
      f16x8 bf = *reinterpret_cast<const f16x8*>(
          &Ws[(wc * 64 + ni * 16 + ln15) * 136 + s * 32 + quad * 8]);
      acc[0][ni] = __builtin_amdgcn_mfma_f32_16x16x32_f16(a0, bf, acc[0][ni], 0, 0, 0);
      acc[1][ni] = __builtin_amdgcn_mfma_f32_16x16x32_f16(a1, bf, acc[1][ni], 0, 0, 0);
    }
  }

  #pragma unroll
  for (int ni = 0; ni < 4; ++ni) {
    const int col = wc * 64 + ni * 16 + ln15;
    float bias = b5[col];
    #pragma unroll
    for (int mi = 0; mi < 2; ++mi) {
      #pragma unroll
      for (int r = 0; r < 4; ++r) {
        int row = row0 + wr * 32 + mi * 16 + quad * 4 + r;
        if (row >= N) continue;
        size_t idx = (size_t)row * HDIM + col;
        float v = acc[mi][ni][r] + bias + outi[idx];  // + hpre
        float ht = tanhf(v);
        float z = 1.f / (1.f + expf(-(float)zb[idx]));
        float o = z * hi[idx] + (1.f - z) * ht;
        outi[idx] = o;
        xb[idx] = (f16)o;
      }
    }
  }
}

extern "C" void kernel_launch(void* const* d_in, const int* in_sizes, int n_in,
                              void* d_out, int out_size, void* d_ws, size_t ws_size,
                              hipStream_t stream) {
  const float* inp = (const float*)d_in[0];
  const int*   edg = (const int*)d_in[1];
  const float* h   = (const float*)d_in[2];
  const float* W   = (const float*)d_in[3];
  const float* b   = (const float*)d_in[4];
  float* out = (float*)d_out;

  const int NH = in_sizes[0];      // N*H
  const int N  = NH / HDIM;
  const int E  = in_sizes[1] / 2;
  const int L  = in_sizes[2] / NH;

  f16* Af   = (f16*)d_ws;               // A aggregate / Ctot (reused)
  f16* Bhf  = Af + (size_t)NH;          // Bh aggregate
  f16* zbuf = Bhf + (size_t)NH;         // zpre
  f16* cbuf = zbuf + (size_t)NH;        // r*h
  f16* xbuf = cbuf + (size_t)NH;        // x f16
  f16* hbuf = xbuf + (size_t)NH;        // h_i f16
  f16* WT   = hbuf + (size_t)NH;        // L*6*H*H transposed f16 weights
  int* deg     = (int*)(WT + (size_t)L * 6 * HDIM * HDIM);
  int* offs    = deg + N;               // N+1
  int* bsum    = offs + (N + 1);        // 256
  int* boff    = bsum + 256;            // 256
  u16* rank    = (u16*)(boff + 256);    // E
  u16* csr_src = rank + (size_t)E;      // E

  const int eblocks = (E + 255) / 256;
  const int fblocks = (E + 1023) / 1024;
  const int nodeblocks = (N + 3) / 4;
  const int n4 = NH / 4;
  const int cvblocks = (n4 + 255) / 256;
  const int rowblocks = (N + 63) / 64;
  const int chunk = (N + 255) / 256;    // <=256 requires N<=65536

  // ---- one-time per call: CSR build, weight transpose, input f16 ----
  hipMemsetAsync(deg, 0, (size_t)N * sizeof(int), stream);
  hipLaunchKernelGGL(degrank_kernel, dim3(eblocks), dim3(256), 0, stream,
                     edg, deg, rank, E);
  hipLaunchKernelGGL(scan_part_kernel, dim3(256), dim3(256), 0, stream,
                     deg, bsum, N, chunk);
  hipLaunchKernelGGL(scan_top_kernel, dim3(1), dim3(256), 0, stream,
                     bsum, boff, offs, N);
  hipLaunchKernelGGL(scan_fin_kernel, dim3(256), dim3(256), 0, stream,
                     deg, boff, offs, N, chunk);
  hipLaunchKernelGGL(fill_kernel, dim3(fblocks), dim3(256), 0, stream,
                     edg, offs, rank, csr_src, E);
  hipLaunchKernelGGL(transw_kernel, dim3(16, L * 6), dim3(256), 0, stream,
                     W, WT);
  hipLaunchKernelGGL(convh_kernel, dim3(cvblocks), dim3(256), 0, stream,
                     inp, xbuf, n4);

  const float* x = inp;
  for (int i = 0; i < L; ++i) {
    const float* hi = h + (size_t)i * NH;
    const f16* WTi = WT + (size_t)i * 6 * HDIM * HDIM;
    const float* bi = b + (size_t)i * 6 * HDIM;
    float* outi = out + (size_t)i * NH;

    hipLaunchKernelGGL(convh_kernel, dim3(cvblocks), dim3(256), 0, stream,
                       hi, hbuf, n4);
    hipLaunchKernelGGL(pull2_kernel, dim3(nodeblocks), dim3(256), 0, stream,
                       csr_src, offs, x, hi, xbuf, hbuf, Af, Bhf, N);
    hipLaunchKernelGGL(gemm3_kernel, dim3(rowblocks, 3), dim3(256), 0, stream,
                       Af, Bhf, WTi, bi, hi, zbuf, cbuf, outi, N);
    hipLaunchKernelGGL(pull1_kernel, dim3(nodeblocks), dim3(256), 0, stream,
                       csr_src, offs, cbuf, Af, N);   // Af reused as Ctot
    hipLaunchKernelGGL(gemm_final_kernel, dim3(rowblocks), dim3(256), 0, stream,
                       Af, WTi + (size_t)5 * HDIM * HDIM, bi + 5 * HDIM,
                       zbuf, hi, outi, xbuf, N);
    x = outi;
  }
}